// Round 14
// baseline (307.282 us; speedup 1.0000x reference)
//
#include <hip/hip_runtime.h>
#include <hip/hip_bf16.h>

#define DEV static __device__ __forceinline__

constexpr float SM_SCALE = 0.125f;   // hd^-0.5, hd=64

typedef __attribute__((ext_vector_type(8))) short s16x8;
typedef __attribute__((ext_vector_type(8))) unsigned short u16x8;
typedef __attribute__((ext_vector_type(4))) unsigned short u16x4;
typedef __attribute__((ext_vector_type(4))) float f32x4;

DEV float bf2f(unsigned short u) {
  union { unsigned int i; float f; } v; v.i = ((unsigned int)u) << 16; return v.f;
}
DEV unsigned short f2bf(float f) {
  union { float f; unsigned int i; } v; v.f = f;
  unsigned int r = v.i + 0x7fffu + ((v.i >> 16) & 1u);
  return (unsigned short)(r >> 16);
}
DEV void tri_unrank(int r, int& k, int& i) {
  k = (int)((sqrtf(8.f * r + 1.f) - 1.f) * 0.5f);
  while (k * (k + 1) / 2 > r) --k;
  while ((k + 1) * (k + 2) / 2 <= r) ++k;
  i = r - k * (k + 1) / 2;
}
// async global->LDS, 16B per lane; dest must be wave-linear (base + lane*16)
DEV void glds16(const void* g, void* l) {
  __builtin_amdgcn_global_load_lds(
      (const __attribute__((address_space(1))) void*)g,
      (__attribute__((address_space(3))) void*)l, 16, 0, 0);
}
DEV void pipe_drain_barrier() {
  asm volatile("s_waitcnt vmcnt(0)" ::: "memory");
  __builtin_amdgcn_s_barrier();
}

// ---------- workspace layout (bytes) ----------
constexpr size_t OFF_XB   = 0;                       // 4MB xb bf16 [2048][1024]
constexpr size_t OFF_WQT  = 4194304;                 // 2MB
constexpr size_t OFF_WKT  = 6291456;                 // 2MB
constexpr size_t OFF_WVT  = 8388608;
constexpr size_t OFF_WOT  = 10485760;
constexpr size_t OFF_W1C  = 12582912;                // 128KB bf16 Ww1 cast (1024x64)
constexpr size_t OFF_W2T  = 12713984;                // 128KB
constexpr size_t OFF_BETA = 12582912;                // reuse W1C after wfuse
constexpr size_t OFF_Q16  = 12845056;                // 4MB bf16 2048x1024
constexpr size_t OFF_K16  = 17039360;                // 4MB
constexpr size_t OFF_VT   = 21233664;                // 4MB  VT[b][64h*d][1024n]
constexpr size_t OFF_WN16 = 25427968;                // 4MB; holds WfusedT until wnorm2
constexpr size_t OFF_WB16 = 29622272;                // 4MB
constexpr size_t OFF_WNF  = 33816576;                // 4MB (reused as Ob)
constexpr size_t OFF_OB   = 33816576;
constexpr size_t OFF_BFT  = 38010880;                // 256KB bf16 (128x1024)
constexpr size_t OFF_FC   = 38273024;                // 128KB
constexpr size_t OFF_L    = 38404096;                // 64MB, stores -L (reused as S)
constexpr size_t OFF_CT   = 105512960;               // 64MB
constexpr size_t OFF_G    = 172621824;               // 64MB, stores -G
constexpr size_t OFF_BL   = 239730688;               // 512KB f32 2048x64
constexpr size_t OFF_U128 = 244187136;               // 8MB bf16 [32][8][128][128]
constexpr size_t OFF_B256 = 252575744;               // 4MB bf16 [32][4][128][128]

// ================= fused prep: transposes + casts + BFT(128 rows); grid 2160 =================
__global__ __launch_bounds__(256) void prep_all(
    const float* __restrict__ W0, const float* __restrict__ W1,
    const float* __restrict__ W2, const float* __restrict__ W3,
    const float* __restrict__ Ww1, const float* __restrict__ Ww2,
    const float* __restrict__ x, const float* __restrict__ Wb,
    const float* __restrict__ Wf,
    unsigned short* __restrict__ D0, unsigned short* __restrict__ D1,
    unsigned short* __restrict__ D2, unsigned short* __restrict__ D3,
    unsigned short* __restrict__ W1c, unsigned short* __restrict__ W2T,
    unsigned short* __restrict__ xb, unsigned short* __restrict__ BFT) {
  int bidx = blockIdx.x;
  int t = threadIdx.x;
  if (bidx >= 2096) {                      // BFT build (64 blocks, 128x1024)
    int e0 = ((bidx - 2096) * 256 + t) * 8;
    int j = e0 >> 10, i0 = e0 & 1023;
    u16x8 o;
#pragma unroll
    for (int e = 0; e < 8; ++e) {
      int i = i0 + e;
      float v = 0.f;
      if (j < 16) v = Wb[i * 16 + j];
      else if (j < 32) v = Wf[i * 16 + (j - 16)];
      o[e] = f2bf(v);
    }
    *(u16x8*)(BFT + e0) = o;
    return;
  }
  if (bidx >= 2064) {                      // W1 cast (32 blocks)
    int i = ((bidx - 2064) * 256 + t) * 8;
    float4 a = *(const float4*)(Ww1 + i);
    float4 b = *(const float4*)(Ww1 + i + 4);
    u16x8 o;
    o[0] = f2bf(a.x); o[1] = f2bf(a.y); o[2] = f2bf(a.z); o[3] = f2bf(a.w);
    o[4] = f2bf(b.x); o[5] = f2bf(b.y); o[6] = f2bf(b.z); o[7] = f2bf(b.w);
    *(u16x8*)(W1c + i) = o;
    return;
  }
  if (bidx >= 1040) {                      // x cast (1024 blocks)
    int i = ((bidx - 1040) * 256 + t) * 8;
    float4 a = *(const float4*)(x + i);
    float4 b = *(const float4*)(x + i + 4);
    u16x8 o;
    o[0] = f2bf(a.x); o[1] = f2bf(a.y); o[2] = f2bf(a.z); o[3] = f2bf(a.w);
    o[4] = f2bf(b.x); o[5] = f2bf(b.y); o[6] = f2bf(b.z); o[7] = f2bf(b.w);
    *(u16x8*)(xb + i) = o;
    return;
  }
  const float* src; unsigned short* dst; int R, C, c0, r0;
  if (bidx >= 1024) {                      // W2T transpose (16 blocks)
    src = Ww2; dst = W2T; R = 64; C = 1024;
    c0 = (bidx - 1024) * 64; r0 = 0;
  } else {
    int z = bidx >> 8, xy = bidx & 255;
    src = z == 0 ? W0 : z == 1 ? W1 : z == 2 ? W2 : W3;
    dst = z == 0 ? D0 : z == 1 ? D1 : z == 2 ? D2 : D3;
    R = 1024; C = 1024;
    c0 = (xy & 15) * 64; r0 = (xy >> 4) * 64;
  }
  __shared__ float tile[64 * 65];
#pragma unroll
  for (int i = 0; i < 16; ++i) {
    int lin = t + i * 256; int r = lin >> 6, c = lin & 63;
    tile[r * 65 + c] = src[(size_t)(r0 + r) * C + c0 + c];
  }
  __syncthreads();
#pragma unroll
  for (int i = 0; i < 16; ++i) {
    int lin = t + i * 256; int c = lin >> 6, r = lin & 63;
    dst[(size_t)(c0 + c) * R + r0 + r] = f2bf(tile[r * 65 + c]);
  }
}

// beta + log_sigmoid + cumsum fused; grid 32 (bh)
__global__ __launch_bounds__(256) void bgfc(const float* __restrict__ BL,
    const float* __restrict__ delta, float* __restrict__ Beta, float* __restrict__ Fc) {
  int bh = blockIdx.x;
  int b = bh >> 4, h = bh & 15;
  int t = threadIdx.x;
  __shared__ float buf[1024];
  __shared__ float tsum[256];
  float dh = delta[h];
#pragma unroll
  for (int i = 0; i < 4; ++i) {
    int n = t + i * 256;
    int row = (b << 10) + n;
    float braw = BL[row * 64 + h];
    Beta[row * 16 + h] = 2.f / (1.f + __expf(-braw));
    float lraw = BL[row * 64 + 16 + h] + dh;
    buf[n] = (lraw >= 0.f) ? -log1pf(__expf(-lraw)) : (lraw - log1pf(__expf(lraw)));
  }
  __syncthreads();
  float loc[4]; float run = 0.f;
#pragma unroll
  for (int i = 0; i < 4; ++i) { run += buf[t * 4 + i]; loc[i] = run; }
  tsum[t] = run;
  __syncthreads();
  for (int off = 1; off < 256; off <<= 1) {
    float add = (t >= off) ? tsum[t - off] : 0.f;
    __syncthreads();
    tsum[t] += add;
    __syncthreads();
  }
  float excl = tsum[t] - run;
#pragma unroll
  for (int i = 0; i < 4; ++i) Fc[bh * 1024 + t * 4 + i] = excl + loc[i];
}

// ================= mega projection: 256x128 tiles; 264 blocks (1 round) =================
__global__ __launch_bounds__(256) void proj_big(const unsigned short* __restrict__ xb,
    const unsigned short* __restrict__ WqT, const unsigned short* __restrict__ WkT,
    const unsigned short* __restrict__ WvT, const unsigned short* __restrict__ WfT,
    const unsigned short* __restrict__ BFT,
    unsigned short* __restrict__ Q16, unsigned short* __restrict__ K16,
    unsigned short* __restrict__ VT, unsigned short* __restrict__ WNF,
    float* __restrict__ BL) {
  int sg = blockIdx.x;                       // 264 = 8 * 33 exactly
  int virt = (sg % 8) * 33 + (sg / 8);       // bijective chunked XCD swizzle
  const unsigned short *A, *BT; unsigned short* out = nullptr; int m0, n0;
  int mode = 0;
  if (virt < 128) {                          // Q/K: 8my(256) x 16nx(128)
    int my = virt >> 4, nx = virt & 15;
    m0 = my * 256; A = xb;
    if (nx < 8) { BT = WqT; out = Q16; n0 = nx * 128; }
    else { BT = WkT; out = K16; n0 = (nx - 8) * 128; }
  } else if (virt < 192) {                   // VT: 2bz x (4my x 8nx)
    int r = virt - 128; int bz = r >> 5; int rr = r & 31;
    m0 = (rr >> 3) * 256; n0 = (rr & 7) * 128;
    A = WvT; BT = xb + ((size_t)bz << 20); out = VT + ((size_t)bz << 20);
  } else if (virt < 256) {                   // WNF: 8my x 8nx
    int r = virt - 192;
    m0 = (r >> 3) * 256; n0 = (r & 7) * 128;
    A = xb; BT = WfT; out = WNF;
  } else {                                   // BL: 8 blocks (m 256 each)
    m0 = (virt - 256) * 256; n0 = 0;
    A = xb; BT = BFT; mode = 1;
  }
  int t = threadIdx.x;
  int w = t >> 6, l = t & 63;
  int fr = l & 15, fq = l >> 4;
  __shared__ unsigned short sh[49152];       // 96KB: A[2] @0/16384, B[2] @32768/40960
  f32x4 acc[4][8];
#pragma unroll
  for (int m = 0; m < 4; ++m)
#pragma unroll
    for (int c = 0; c < 8; ++c) acc[m][c] = (f32x4){0.f, 0.f, 0.f, 0.f};

#define STAGE_PB(buf, k0) {                                             \
  _Pragma("unroll")                                                     \
  for (int i = 0; i < 8; ++i) {                                         \
    int cid = t + i * 256;                                              \
    int row = cid >> 3, ch = cid & 7;                                   \
    int chs = ch ^ (row & 7);                                           \
    glds16(A + (size_t)(m0 + row) * 1024 + (k0) + chs * 8,              \
           (char*)(sh + (buf) * 16384) + cid * 16);                     \
  }                                                                     \
  _Pragma("unroll")                                                     \
  for (int i = 0; i < 4; ++i) {                                         \
    int cid = t + i * 256;                                              \
    int row = cid >> 3, ch = cid & 7;                                   \
    int chs = ch ^ (row & 7);                                           \
    glds16(BT + (size_t)(n0 + row) * 1024 + (k0) + chs * 8,             \
           (char*)(sh + 32768 + (buf) * 8192) + cid * 16);              \
  } }

  STAGE_PB(0, 0);
  pipe_drain_barrier();
  int cur = 0;
  for (int kt = 0; kt < 16; ++kt) {
    if (kt < 15) STAGE_PB(cur ^ 1, (kt + 1) * 64);
    const char* Ab = (const char*)(sh + cur * 16384);
    const char* Bb = (const char*)(sh + 32768 + cur * 8192);
    __builtin_amdgcn_s_setprio(1);
#pragma unroll
    for (int kh = 0; kh < 2; ++kh) {
      s16x8 af[4];
#pragma unroll
      for (int m = 0; m < 4; ++m) {
        int ra = 64 * w + 16 * m + fr;
        af[m] = *(const s16x8*)(Ab + (((ra << 7) + (kh << 6) + (fq << 4)) ^ ((ra & 7) << 4)));
      }
#pragma unroll
      for (int c = 0; c < 8; ++c) {
        int rb = 16 * c + fr;
        s16x8 bb = *(const s16x8*)(Bb + (((rb << 7) + (kh << 6) + (fq << 4)) ^ ((rb & 7) << 4)));
#pragma unroll
        for (int m = 0; m < 4; ++m)
          acc[m][c] = __builtin_amdgcn_mfma_f32_16x16x32_bf16(af[m], bb, acc[m][c], 0, 0, 0);
      }
    }
    __builtin_amdgcn_s_setprio(0);
    pipe_drain_barrier();
    cur ^= 1;
  }
#undef STAGE_PB
#pragma unroll
  for (int m = 0; m < 4; ++m) {
#pragma unroll
    for (int c = 0; c < 8; ++c) {
      int col = n0 + 16 * c + fr;
#pragma unroll
      for (int r = 0; r < 4; ++r) {
        int grow = m0 + 64 * w + 16 * m + fq * 4 + r;
        if (mode == 0) out[(size_t)grow * 1024 + col] = f2bf(acc[m][c][r]);
        else if (col < 64) BL[(size_t)grow * 64 + col] = acc[m][c][r];
      }
    }
  }
}

// ================= 64-tile bf16 NT GEMM; 2-phase pipeline =================
template<int F32OUT>
__global__ __launch_bounds__(256) void gemm_nt(const unsigned short* __restrict__ A,
    const unsigned short* __restrict__ BT, void* __restrict__ out,
    int M, int N, int K) {
  __shared__ unsigned short As[2 * 4096];
  __shared__ unsigned short Bs[2 * 4096];
  int m0 = blockIdx.y * 64, n0 = blockIdx.x * 64;
  int t = threadIdx.x;
  int w = t >> 6, l = t & 63, fr = l & 15;
  int koB = (l >> 4) * 16;
  f32x4 acc[4];
#pragma unroll
  for (int c = 0; c < 4; ++c) acc[c] = (f32x4){0.f, 0.f, 0.f, 0.f};

#define STAGE_G(buf, k0) {                                              \
  _Pragma("unroll")                                                     \
  for (int i = 0; i < 2; ++i) {                                         \
    int cid = t + i * 256;                                              \
    int row = cid >> 3, ch = cid & 7;                                   \
    int chs = ch ^ (row & 7);                                           \
    glds16(A + (size_t)(m0 + row) * K + (k0) + chs * 8, (char*)(As + (buf) * 4096) + cid * 16); \
    glds16(BT + (size_t)(n0 + row) * K + (k0) + chs * 8, (char*)(Bs + (buf) * 4096) + cid * 16); \
  } }

  int nt = K >> 6;
  STAGE_G(0, 0);
  pipe_drain_barrier();
  int cur = 0;
  for (int kt = 0; kt < nt; ++kt) {
    if (kt + 1 < nt) STAGE_G(cur ^ 1, (kt + 1) * 64);
    const char* Ab = (const char*)(As + cur * 4096);
    const char* Bb = (const char*)(Bs + cur * 4096);
    __builtin_amdgcn_s_setprio(1);
#pragma unroll
    for (int kh = 0; kh < 2; ++kh) {
      int ra = 16 * w + fr;
      s16x8 a = *(const s16x8*)(Ab + (((ra << 7) + (kh << 6) + koB) ^ ((ra & 7) << 4)));
#pragma unroll
      for (int c = 0; c < 4; ++c) {
        int rb = 16 * c + fr;
        s16x8 bb = *(const s16x8*)(Bb + (((rb << 7) + (kh << 6) + koB) ^ ((rb & 7) << 4)));
        acc[c] = __builtin_amdgcn_mfma_f32_16x16x32_bf16(a, bb, acc[c], 0, 0, 0);
      }
    }
    __builtin_amdgcn_s_setprio(0);
    pipe_drain_barrier();
    cur ^= 1;
  }
#undef STAGE_G
  int rbase = m0 + 16 * w + ((l >> 4) << 2);
#pragma unroll
  for (int c = 0; c < 4; ++c) {
    int col = n0 + 16 * c + fr;
#pragma unroll
    for (int r = 0; r < 4; ++r) {
      if (F32OUT) ((float*)out)[(size_t)(rbase + r) * N + col] = acc[c][r];
      else ((unsigned short*)out)[(size_t)(rbase + r) * N + col] = f2bf(acc[c][r]);
    }
  }
}

// ================= output projection: 64-tile, XCD-grouped 512 blocks, f32 out =================
__global__ __launch_bounds__(256) void gemm_outproj(const unsigned short* __restrict__ A,
    const unsigned short* __restrict__ BT, float* __restrict__ out) {
  int sg = blockIdx.x;                       // 512 = 8 * 64 exactly
  int virt = (sg & 7) * 64 + (sg >> 3);      // each XCD: one 8x8 panel group (2MB WS)
  int g = virt >> 6, in = virt & 63;
  int my = (g >> 1) * 8 + (in >> 3);         // 0..31
  int nx = (g & 1) * 8 + (in & 7);           // 0..15
  int m0 = my * 64, n0 = nx * 64;
  const int K = 1024, N = 1024;
  __shared__ unsigned short As[2 * 4096];
  __shared__ unsigned short Bs[2 * 4096];
  int t = threadIdx.x;
  int w = t >> 6, l = t & 63, fr = l & 15;
  int koB = (l >> 4) * 16;
  f32x4 acc[4];
#pragma unroll
  for (int c = 0; c < 4; ++c) acc[c] = (f32x4){0.f, 0.f, 0.f, 0.f};

#define STAGE_O(buf, k0) {                                              \
  _Pragma("unroll")                                                     \
  for (int i = 0; i < 2; ++i) {                                         \
    int cid = t + i * 256;                                              \
    int row = cid >> 3, ch = cid & 7;                                   \
    int chs = ch ^ (row & 7);                                           \
    glds16(A + (size_t)(m0 + row) * K + (k0) + chs * 8, (char*)(As + (buf) * 4096) + cid * 16); \
    glds16(BT + (size_t)(n0 + row) * K + (k0) + chs * 8, (char*)(Bs + (buf) * 4096) + cid * 16); \
  } }

  STAGE_O(0, 0);
  pipe_drain_barrier();
  int cur = 0;
  for (int kt = 0; kt < 16; ++kt) {
    if (kt + 1 < 16) STAGE_O(cur ^ 1, (kt + 1) * 64);
    const char* Ab = (const char*)(As + cur * 4096);
    const char* Bb = (const char*)(Bs + cur * 4096);
    __builtin_amdgcn_s_setprio(1);
#pragma unroll
    for (int kh = 0; kh < 2; ++kh) {
      int ra = 16 * w + fr;
      s16x8 a = *(const s16x8*)(Ab + (((ra << 7) + (kh << 6) + koB) ^ ((ra & 7) << 4)));
#pragma unroll
      for (int c = 0; c < 4; ++c) {
        int rb = 16 * c + fr;
        s16x8 bb = *(const s16x8*)(Bb + (((rb << 7) + (kh << 6) + koB) ^ ((rb & 7) << 4)));
        acc[c] = __builtin_amdgcn_mfma_f32_16x16x32_bf16(a, bb, acc[c], 0, 0, 0);
      }
    }
    __builtin_amdgcn_s_setprio(0);
    pipe_drain_barrier();
    cur ^= 1;
  }
#undef STAGE_O
  int rbase = m0 + 16 * w + ((l >> 4) << 2);
#pragma unroll
  for (int c = 0; c < 4; ++c) {
    int col = n0 + 16 * c + fr;
#pragma unroll
    for (int r = 0; r < 4; ++r)
      out[(size_t)(rbase + r) * N + col] = acc[c][r];
  }
}

// ================= w normalize + beta-scale =================
__global__ __launch_bounds__(256) void wnorm2(const unsigned short* __restrict__ WNF,
    const float* __restrict__ Beta, unsigned short* __restrict__ WN,
    unsigned short* __restrict__ WB) {
  int row = blockIdx.x;
  int wave = threadIdx.x >> 6, lane = threadIdx.x & 63;
#pragma unroll
  for (int i = 0; i < 4; ++i) {
    int hh = wave * 4 + i;
    size_t idx = ((size_t)row << 10) + hh * 64 + lane;
    float v = bf2f(WNF[idx]);
    float ss = v * v;
#pragma unroll
    for (int off = 1; off < 64; off <<= 1) ss += __shfl_xor(ss, off);
    float wn = v * rsqrtf(ss + 1e-6f);
    WN[idx] = f2bf(wn);
    WB[idx] = f2bf(wn * Beta[row * 16 + hh]);
  }
}

// ================= pair fused: writes NEGATED L and G =================
__global__ __launch_bounds__(256) void pairLG(const unsigned short* __restrict__ WN,
    const unsigned short* __restrict__ Q, const unsigned short* __restrict__ WB,
    unsigned short* __restrict__ Lg, unsigned short* __restrict__ Gg) {
  int idx = blockIdx.x;
  int bh = idx & 31, r0r = idx >> 5;
  int tb2, jb2; tri_unrank(r0r, tb2, jb2);
  int b = bh >> 4, h = bh & 15;
  int m0 = tb2 * 128, n0 = jb2 * 128;
  int t = threadIdx.x;
  int w = t >> 6, l = t & 63;
  int wr = w >> 1, wc = w & 1;
  int fr = l & 15, fq = l >> 4;
  __shared__ unsigned short As[128 * 64];
  __shared__ unsigned short Bs[128 * 64];
  const unsigned short* WNb = WN + ((size_t)b << 20) + h * 64;
  const unsigned short* Qb  = Q + ((size_t)b << 20) + h * 64;
  const unsigned short* WBb = WB + ((size_t)b << 20) + h * 64;
  size_t base = (size_t)bh << 20;
#pragma unroll
  for (int i = 0; i < 4; ++i) {
    int cid = t + i * 256;
    int row = cid >> 3, ch = cid & 7;
    int chs = ch ^ (row & 7);
    glds16(WNb + ((size_t)(m0 + row) << 10) + chs * 8, (char*)As + cid * 16);
    glds16(WBb + ((size_t)(n0 + row) << 10) + chs * 8, (char*)Bs + cid * 16);
  }
  __syncthreads();
  for (int pass = 0; pass < 2; ++pass) {
    f32x4 acc[4][4];
#pragma unroll
    for (int m = 0; m < 4; ++m)
#pragma unroll
      for (int c = 0; c < 4; ++c) acc[m][c] = (f32x4){0.f, 0.f, 0.f, 0.f};
#pragma unroll
    for (int kh = 0; kh < 2; ++kh) {
      s16x8 af[4], bfv[4];
#pragma unroll
      for (int m = 0; m < 4; ++m) {
        int ra = wr * 64 + 16 * m + fr;
        af[m] = *(const s16x8*)((char*)As + (((ra << 7) + (kh << 6) + (fq << 4)) ^ ((ra & 7) << 4)));
      }
#pragma unroll
      for (int c = 0; c < 4; ++c) {
        int rb = wc * 64 + 16 * c + fr;
        bfv[c] = *(const s16x8*)((char*)Bs + (((rb << 7) + (kh << 6) + (fq << 4)) ^ ((rb & 7) << 4)));
      }
#pragma unroll
      for (int m = 0; m < 4; ++m)
#pragma unroll
        for (int c = 0; c < 4; ++c)
          acc[m][c] = __builtin_amdgcn_mfma_f32_16x16x32_bf16(af[m], bfv[c], acc[m][c], 0, 0, 0);
    }
    unsigned short* dst = pass ? Gg : Lg;
#pragma unroll
    for (int m = 0; m < 4; ++m) {
#pragma unroll
      for (int c = 0; c < 4; ++c) {
        int gj = n0 + wc * 64 + 16 * c + fr;
#pragma unroll
        for (int r = 0; r < 4; ++r) {
          int gi = m0 + wr * 64 + 16 * m + fq * 4 + r;
          bool keep = pass ? (gj <= gi) : (gj < gi);
          dst[base + ((size_t)gi << 10) + gj] = f2bf(keep ? -acc[m][c][r] : 0.f);
        }
      }
    }
    if (pass == 0) {
      __syncthreads();
#pragma unroll
      for (int i = 0; i < 4; ++i) {
        int cid = t + i * 256;
        int row = cid >> 3, ch = cid & 7;
        int chs = ch ^ (row & 7);
        glds16(Qb + ((size_t)(m0 + row) << 10) + chs * 8, (char*)As + cid * 16);
      }
      __syncthreads();
    }
  }
}

// ================= score: S = Q K^T + Gneg @ C, sorted 1D grid; 2-phase pipeline =================
__global__ __launch_bounds__(256) void score128s(const unsigned short* __restrict__ Q,
    const unsigned short* __restrict__ Kk, const unsigned short* __restrict__ G,
    const unsigned short* __restrict__ CT, unsigned short* __restrict__ Sg) {
  int idx = blockIdx.x;
  int bh = idx & 31, r0r = idx >> 5;
  int k, i; tri_unrank(r0r, k, i);
  int tb2 = (7 - k) + i, jb2 = i;
  int b = bh >> 4, h = bh & 15;
  int m0 = tb2 * 128, n0 = jb2 * 128;
  int t = threadIdx.x;
  int w = t >> 6, l = t & 63;
  int wr = w >> 1, wc = w & 1;
  int fr = l & 15, fq = l >> 4;
  __shared__ unsigned short As[2 * 8192];
  __shared__ unsigned short Bs[2 * 8192];
  size_t base = (size_t)bh << 20;
  const unsigned short* Qb_ = Q + ((size_t)b << 20) + h * 64;
  const unsigned short* Kb_ = Kk + ((size_t)b << 20) + h * 64;
  const unsigned short* Gb_ = G + base;
  const unsigned short* Cb_ = CT + base;
  int kbase = jb2 * 128;
  int nsteps = 1 + (tb2 - jb2 + 1) * 2;
  f32x4 acc[4][4];
#pragma unroll
  for (int m = 0; m < 4; ++m)
#pragma unroll
    for (int c = 0; c < 4; ++c) acc[m][c] = (f32x4){0.f, 0.f, 0.f, 0.f};

#define STAGE_SC(buf, stp) {                                            \
  const unsigned short* pa; const unsigned short* pb; int koff;         \
  if ((stp) == 0) { pa = Qb_; pb = Kb_; koff = 0; }                     \
  else { pa = Gb_; pb = Cb_; koff = kbase + ((stp) - 1) * 64; }         \
  _Pragma("unroll")                                                     \
  for (int i2 = 0; i2 < 4; ++i2) {                                      \
    int cid = t + i2 * 256;                                             \
    int row = cid >> 3, ch = cid & 7;                                   \
    int chs = ch ^ (row & 7);                                           \
    glds16(pa + ((size_t)(m0 + row) << 10) + koff + chs * 8, (char*)(As + (buf) * 8192) + cid * 16); \
    glds16(pb + ((size_t)(n0 + row) << 10) + koff + chs * 8, (char*)(Bs + (buf) * 8192) + cid * 16); \
  } }

  STAGE_SC(0, 0);
  pipe_drain_barrier();
  int cur = 0;
  for (int step = 0; step < nsteps; ++step) {
    if (step + 1 < nsteps) STAGE_SC(cur ^ 1, step + 1);
    const char* Ab = (const char*)(As + cur * 8192);
    const char* Bb = (const char*)(Bs + cur * 8192);
    __builtin_amdgcn_s_setprio(1);
#pragma unroll
    for (int kh = 0; kh < 2; ++kh) {
      s16x8 af[4], bfv[4];
#pragma unroll
      for (int m = 0; m < 4; ++m) {
        int ra = wr * 64 + 16 * m + fr;
        af[m] = *(const s16x8*)(Ab + (((ra << 7) + (kh << 6) + (fq << 4)) ^ ((ra & 7) << 4)));
      }
#pragma unroll
      for (int c = 0; c < 4; ++c) {
        int rb = wc * 64 + 16 * c + fr;
        bfv[c] = *(const s16x8*)(Bb + (((rb << 7) + (kh << 6) + (fq << 4)) ^ ((rb & 7) << 4)));
      }
#pragma unroll
      for (int m = 0; m < 4; ++m)
#pragma unroll
        for (int c = 0; c < 4; ++c)
          acc[m][c] = __builtin_amdgcn_mfma_f32_16x16x32_bf16(af[m], bfv[c], acc[m][c], 0, 0, 0);
    }
    __builtin_amdgcn_s_setprio(0);
    pipe_drain_barrier();
    cur ^= 1;
  }
#undef STAGE_SC
#pragma unroll
  for (int m = 0; m < 4; ++m) {
#pragma unroll
    for (int c = 0; c < 4; ++c) {
      int gj = n0 + wc * 64 + 16 * c + fr;
#pragma unroll
      for (int r = 0; r < 4; ++r) {
        int gi = m0 + wr * 64 + 16 * m + fq * 4 + r;
        Sg[base + ((size_t)gi << 10) + gj] = f2bf(acc[m][c][r]);
      }
    }
  }
}

// ================= invbuild: 2x inv64 + U128 assembly in one block; grid (8,32) =================
__global__ __launch_bounds__(256) void invbuild(const unsigned short* __restrict__ Lb,
    unsigned short* __restrict__ U128) {
  int ib = blockIdx.x, bh = blockIdx.y;
  int t = threadIdx.x, w = t >> 6, l = t & 63, fr = l & 15, fq = l >> 4;
  int s0 = ib * 128;
  size_t base = (size_t)bh << 20;
  unsigned short* Uo = U128 + (((size_t)(bh * 8 + ib)) << 14);
  __shared__ float LD[2][64 * 65];
  __shared__ unsigned short UaR[64 * 72];
  __shared__ unsigned short UcR[64 * 72];
  __shared__ unsigned short UaT[64 * 64];
  __shared__ unsigned short T1T[64 * 64];
#pragma unroll
  for (int i = 0; i < 32; ++i) {
    int lin = t + i * 256;
    int blk = lin >> 12, s = (lin >> 6) & 63, r = lin & 63;
    LD[blk][s * 65 + r] = -bf2f(Lb[base + ((size_t)(s0 + blk * 64 + s) << 10) + s0 + blk * 64 + r]);
  }
  __syncthreads();
  if (t < 128) {
    int blk = t >> 6, j = t & 63;
    const float* ld = LD[blk];
    float cc[64];
#pragma unroll
    for (int s = 0; s < 64; ++s) cc[s] = (s == j) ? 1.f : 0.f;
#pragma unroll
    for (int r = 0; r < 63; ++r) {
      float val = cc[r];
#pragma unroll
      for (int s = r + 1; s < 64; ++s) cc[s] -= ld[s * 65 + r] * val;
    }
    if (blk == 0) {
#pragma unroll
      for (int s = 0; s < 64; ++s) {
        unsigned short v = f2bf(cc[s]);
        UaR[s * 72 + j] = v;
        *(unsigned short*)((char*)UaT + (((j << 7) + (s << 1)) ^ ((j & 7) << 4))) = v;
      }
    } else {
#pragma unroll
      for (int s = 0; s < 64; ++s) UcR[s * 72 + j] = f2bf(cc[s]);
    }
  }
  __syncthreads();
#pragma unroll
  for (int i = 0; i < 8; ++i) {
    int cid = t + i * 256;
    int row = cid >> 4, ch = cid & 15;
    u16x8 v = {0, 0, 0, 0, 0, 0, 0, 0};
    if (row < 64) {
      if (ch < 8) {
#pragma unroll
        for (int e = 0; e < 8; ++e) v[e] = UaR[row * 72 + ch * 8 + e];
      }
      *(u16x8*)(Uo + row * 128 + ch * 8) = v;
    } else if (ch >= 8) {
#pragma unroll
      for (int e = 0; e < 8; ++e) v[e] = UcR[(row - 64) * 72 + (ch - 8) * 8 + e];
      *(u16x8*)(Uo + row * 128 + ch * 8) = v;
    }
  }
  f32x4 a1[4];
#pragma unroll
  for (int c = 0; c < 4; ++c) a1[c] = (f32x4){0.f, 0.f, 0.f, 0.f};
#pragma unroll
  for (int kc = 0; kc < 2; ++kc) {
    s16x8 af = *(const s16x8*)(Lb + base + ((size_t)(s0 + 64 + 16 * w + fr) << 10) + s0 + kc * 32 + fq * 8);
#pragma unroll
    for (int c = 0; c < 4; ++c) {
      int j = 16 * c + fr;
      s16x8 bb = *(const s16x8*)((char*)UaT + (((j << 7) + (kc << 6) + (fq << 4)) ^ ((j & 7) << 4)));
      a1[c] = __builtin_amdgcn_mfma_f32_16x16x32_bf16(af, bb, a1[c], 0, 0, 0);
    }
  }
#pragma unroll
  for (int c = 0; c < 4; ++c) {
    int gj = 16 * c + fr;
    int sb = 16 * w + fq * 4;
    u16x4 pk;
#pragma unroll
    for (int r = 0; r < 4; ++r) pk[r] = f2bf(a1[c][r]);
    *(u16x4*)((char*)T1T + (((gj << 7) + (sb << 1)) ^ ((gj & 7) << 4))) = pk;
  }
  __syncthreads();
  f32x4 a2[4];
#pragma unroll
  for (int c = 0; c < 4; ++c) a2[c] = (f32x4){0.f, 0.f, 0.f, 0.f};
#pragma unroll
  for (int kc = 0; kc < 2; ++kc) {
    s16x8 af = *(const s16x8*)(UcR + (16 * w + fr) * 72 + kc * 32 + fq * 8);
#pragma unroll
    for (int c = 0; c < 4; ++c) {
      int j = 16 * c + fr;
      s16x8 bb = *(const s16x8*)((char*)T1T + (((j << 7) + (kc << 6) + (fq << 4)) ^ ((j & 7) << 4)));
      a2[c] = __builtin_amdgcn_mfma_f32_16x16x32_bf16(af, bb, a2[c], 0, 0, 0);
    }
  }
#pragma unroll
  for (int c = 0; c < 4; ++c) {
    int gj = 16 * c + fr;
#pragma unroll
    for (int r = 0; r < 4; ++r)
      Uo[(64 + 16 * w + fq * 4 + r) * 128 + gj] = f2bf(a2[c][r]);
  }
}

// ================= u256build: B256 = Uc128 @ (Lneg_BA @ Ua128); grid (4,32) =================
__global__ __launch_bounds__(256) void u256build(const unsigned short* __restrict__ Lb,
    const unsigned short* __restrict__ U128, unsigned short* __restrict__ B256) {
  int qb = blockIdx.x, bh = blockIdx.y;
  int t = threadIdx.x, w = t >> 6, l = t & 63, fr = l & 15, fq = l >> 4;
  int s0 = qb * 256;
  size_t base = (size_t)bh << 20;
  const unsigned short* Ua = U128 + (((size_t)(bh * 8 + 2 * qb)) << 14);
  const unsigned short* Uc = U128 + (((size_t)(bh * 8 + 2 * qb + 1)) << 14);
  unsigned short* out = B256 + (((size_t)(bh * 4 + qb)) << 14);
  __shared__ unsigned short UaT[16384];
  __shared__ unsigned short T1T[16384];
#pragma unroll
  for (int i = 0; i < 8; ++i) {
    int cid = t + i * 256;
    int s = cid >> 4, ch = cid & 15;
    u16x8 v = *(const u16x8*)(Ua + s * 128 + ch * 8);
#pragma unroll
    for (int e = 0; e < 8; ++e) {
      int j = ch * 8 + e;
      int byt = ((j << 8) + (s << 1)) ^ ((j & 15) << 4);
      *(unsigned short*)((char*)UaT + byt) = v[e];
    }
  }
  __syncthreads();
  f32x4 a1[2][8];
#pragma unroll
  for (int m = 0; m < 2; ++m)
#pragma unroll
    for (int c = 0; c < 8; ++c) a1[m][c] = (f32x4){0.f, 0.f, 0.f, 0.f};
#pragma unroll
  for (int kc = 0; kc < 4; ++kc) {
    s16x8 af[2];
#pragma unroll
    for (int m = 0; m < 2; ++m)
      af[m] = *(const s16x8*)(Lb + base + ((size_t)(s0 + 128 + 32 * w + 16 * m + fr) << 10) + s0 + kc * 32 + fq * 8);
#pragma unroll
    for (int c = 0; c < 8; ++c) {
      int j = 16 * c + fr;
      s16x8 bb = *(const s16x8*)((char*)UaT + (((j << 8) + (kc << 6) + (fq << 4)) ^ ((j & 15) << 4)));
#pragma unroll
      for (int m = 0; m < 2; ++m)
        a1[m][c] = __builtin_amdgcn_mfma_f32_16x16x32_bf16(af[m], bb, a1[m][c], 0, 0, 0);
    }
  }
#pragma unroll
  for (int m = 0; m < 2; ++m) {
#pragma unroll
    for (int c = 0; c < 8; ++c) {
      int col = 16 * c + fr;
      int row0 = 32 * w + 16 * m + fq * 4;
      u16x4 pk;
#pragma unroll
      for (int r = 0; r < 4; ++r) pk[r] = f2bf(a1[m][c][r]);
      int byt = ((col << 8) + (row0 << 1)) ^ ((col & 15) << 4);
      *(u16x4*)((char*)T1T + byt) = pk;
    }
  }
  __syncthreads();
  f32x4 a2[2][8];
#pragma unroll
  for (int m = 0; m < 2; ++m)
#pragma unroll
    for (int c = 0; c < 8; ++c) a2[m][c] = (f32x4){0.f, 0.f, 0.f, 0.f};
#pragma unroll
  for (int kc = 0; kc < 4; ++kc) {
    s16x8 af[2];
#pragma unroll
    for (int m = 0; m < 2; ++m)
      af[m] = *(const s16x8*)(Uc + (32 * w + 16 * m + fr) * 128 + kc * 32 + fq * 8);
#pragma unroll
    for (int c = 0; c < 8; ++c) {
      int j = 16 * c + fr;
      s16x8 bb = *(const s16x8*)((char*)T1T + (((j << 8) + (kc << 6) + (fq << 4)) ^ ((j & 15) << 4)));
#pragma unroll
      for (int m = 0; m < 2; ++m)
        a2[m][c] = __builtin_amdgcn_mfma_f32_16x16x32_bf16(af[m], bb, a2[m][c], 0, 0, 0);
    }
  }
#pragma unroll
  for (int m = 0; m < 2; ++m) {
#pragma unroll
    for (int c = 0; c < 8; ++c) {
      int col = 16 * c + fr;
#pragma unroll
      for (int r = 0; r < 4; ++r)
        out[(32 * w + 16 * m + fq * 4 + r) * 128 + col] = f2bf(a2[m][c][r]);
    }
  }
}

// ================= solve256: 256-row band step; pipelined band GEMM + 3-piece apply =================
__global__ __launch_bounds__(256) void solve256(const unsigned short* __restrict__ WN,
    const unsigned short* __restrict__ Kk, const unsigned short* __restrict__ Lb,
    const unsigned short* __restrict__ U128, const unsigned short* __restrict__ B256,
    unsigned short* __restrict__ CT, int ib) {
  int jb = blockIdx.x, bh = blockIdx.y;
  int b = bh >> 4, h = bh & 15;
  int t = threadIdx.x, w = t >> 6, l = t & 63, fr = l & 15, fq = l >> 4;
  int s0 = ib * 256, j0 = jb * 128;
  size_t base = (size_t)bh << 20;
  __shared__ unsigned short sh[49152];      // 96KB: As[2] @0/16384, Bs[2] @32768/40960; rT aliases @0
  unsigned short* rT = sh;
  const unsigned short* Wb_ = WN + ((size_t)b << 20) + h * 64;
  const unsigned short* Kb_ = Kk + ((size_t)b << 20) + h * 64;

  f32x4 acc[4][8];
#pragma unroll
  for (int m = 0; m < 4; ++m)
#pragma unroll
    for (int c = 0; c < 8; ++c) acc[m][c] = (f32x4){0.f, 0.f, 0.f, 0.f};
  int nst = 1 + 4 * ib - 2 * jb; if (nst < 1) nst = 1;

#define STAGE_SV(buf, stp) {                                            \
  int rb = 2 * jb + (stp) - 1;                                          \
  _Pragma("unroll")                                                     \
  for (int i = 0; i < 8; ++i) {                                         \
    int cid = t + i * 256;                                              \
    int row = cid >> 3, ch = cid & 7;                                   \
    int chs = ch ^ (row & 7);                                           \
    const unsigned short* ga = ((stp) == 0)                             \
      ? Wb_ + ((size_t)(s0 + row) << 10) + chs * 8                      \
      : Lb + base + ((size_t)(s0 + row) << 10) + rb * 64 + chs * 8;     \
    glds16(ga, (char*)(sh + (buf) * 16384) + cid * 16);                 \
  }                                                                     \
  _Pragma("unroll")                                                     \
  for (int i = 0; i < 4; ++i) {                                         \
    int cid = t + i * 256;                                              \
    int row = cid >> 3, ch = cid & 7;                                   \
    int chs = ch ^ (row & 7);                                           \
    const unsigned short* gb = ((stp) == 0)                             \
      ? Kb_ + ((size_t)(j0 + row) << 10) + chs * 8                      \
      : CT + base + ((size_t)(j0 + row) << 10) + rb * 64 + chs * 8;     \
    glds16(gb, (char*)(sh + 32768 + (buf) * 8192) + cid * 16);          \
  } }

  STAGE_SV(0, 0);
  pipe_drain_barrier();
  int cur = 0;
  for (int st = 0; st < nst; ++st) {
    if (st + 1 < nst) STAGE_SV(cur ^ 1, st + 1);
    const char* Ab = (const char*)(sh + cur * 16384);
    const char* Bb = (const char*)(sh + 32768 + cur * 8192);
    __builtin_amdgcn_s_setprio(1);
#pragma unroll
    for (int kh = 0; kh < 2; ++kh) {
      s16x8 af[4], bfv[8];
#pragma unroll
      for (int m = 0; m < 4; ++m) {
        int ra = 64 * w + 16 * m + fr;
        af[m] = *(const s16x8*)(Ab + (((ra << 7) + (kh << 6) + (fq << 4)) ^ ((ra & 7) << 4)));
      }
#pragma unroll
      for (int c = 0; c < 8; ++c) {
        int rb2 = 16 * c + fr;
        bfv[c] = *(const s16x8*)(Bb + (((rb2 << 7) + (kh << 6) + (fq << 4)) ^ ((rb2 & 7) << 4)));
      }
#pragma unroll
      for (int m = 0; m < 4; ++m)
#pragma unroll
        for (int c = 0; c < 8; ++c)
          acc[m][c] = __builtin_amdgcn_mfma_f32_16x16x32_bf16(af[m], bfv[c], acc[m][c], 0, 0, 0);
    }
    __builtin_amdgcn_s_setprio(0);
    pipe_drain_barrier();
    cur ^= 1;
  }
#undef STAGE_SV
  // write rectT [j][s] (512B rows, XOR (j&15)<<4), mask j >= s
#pragma unroll
  for (int m = 0; m < 4; ++m) {
#pragma unroll
    for (int c = 0; c < 8; ++c) {
      int sl0 = 64 * w + 16 * m + fq * 4;
      int jl = 16 * c + fr;
      u16x4 pk;
#pragma unroll
      for (int r = 0; r < 4; ++r) {
        float v = acc[m][c][r];
        if (j0 + jl >= s0 + sl0 + r) v = 0.f;
        pk[r] = f2bf(v);
      }
      int byt = ((jl << 9) + (sl0 << 1)) ^ ((jl & 15) << 4);
      *(u16x4*)((char*)rT + byt) = pk;
    }
  }
  __syncthreads();
  const unsigned short* Ua = U128 + (((size_t)(bh * 8 + 2 * ib)) << 14);
  const unsigned short* Uc = U128 + (((size_t)(bh * 8 + 2 * ib + 1)) << 14);
  const unsigned short* Bm = B256 + (((size_t)(bh * 4 + ib)) << 14);
#pragma unroll
  for (int m = 0; m < 4; ++m)
#pragma unroll
    for (int c = 0; c < 8; ++c) acc[m][c] = (f32x4){0.f, 0.f, 0.f, 0.f};
  int nkc = (w < 2) ? 4 : 8;
  for (int kc = 0; kc < nkc; ++kc) {
    const unsigned short* src; int arow;
    if (w < 2) { src = Ua; arow = 64 * w; }
    else { src = (kc < 4) ? Bm : Uc; arow = 64 * (w - 2); }
    s16x8 uf[4];
#pragma unroll
    for (int m = 0; m < 4; ++m)
      uf[m] = *(const s16x8*)(src + (arow + 16 * m + fr) * 128 + (kc & 3) * 32 + fq * 8);
#pragma unroll
    for (int c = 0; c < 8; ++c) {
      int jl = 16 * c + fr;
      s16x8 bb = *(const s16x8*)((char*)rT + (((jl << 9) + (kc << 6) + (fq << 4)) ^ ((jl & 15) << 4)));
#pragma unroll
      for (int m = 0; m < 4; ++m)
        acc[m][c] = __builtin_amdgcn_mfma_f32_16x16x32_bf16(uf[m], bb, acc[m][c], 0, 0, 0);
    }
  }
#pragma unroll
  for (int m = 0; m < 4; ++m) {
#pragma unroll
    for (int c = 0; c < 8; ++c) {
      int jl = 16 * c + fr;
      int sb = 64 * w + 16 * m + fq * 4;
      u16x4 pk;
#pragma unroll
      for (int r = 0; r < 4; ++r) pk[r] = f2bf(acc[m][c][r]);
      *(u16x4*)(CT + base + ((size_t)(j0 + jl) << 10) + s0 + sb) = pk;
    }
  }
}

// ================= pv: online-softmax + P @ V; wave-independent (no barriers) =================
__global__ __launch_bounds__(256) void pv_kernel(const unsigned short* __restrict__ S,
    const unsigned short* __restrict__ VT, const float* __restrict__ Fc,
    unsigned short* __restrict__ Ob) {
  int idx = blockIdx.x;
  int bh = idx & 31, rank = idx >> 5;
  int tb = 15 - rank;
  int b = bh >> 4, h = bh & 15;
  int t0 = tb * 64;
  int t = threadIdx.x, w = t >> 6, l = t & 63, fr = l & 15, fq = l >> 4;
  int g = l >> 3, ch = l & 7;              // 8-lane row group / col chunk
  __shared__ unsigned short Pl[4][16 * 64];   // per-wave 2KB region
  size_t base = (size_t)bh << 20;
  float m0 = -1e30f, m1 = -1e30f, l0 = 0.f, l1 = 0.f;
  f32x4 acc[4];
#pragma unroll
  for (int c = 0; c < 4; ++c) acc[c] = (f32x4){0.f,0.f,0.f,0.f};
  for (int jb = 0; jb <= tb; ++jb) {
    int j0 = jb * 64;
    float sc[2];
#pragma unroll
    for (int i = 0; i < 2; ++i) {
      int row16 = g + i * 8;
      int row64 = 16 * w + row16;
      int grow = t0 + row64;
      u16x8 sv = *(const u16x8*)(S + base + ((size_t)grow << 10) + j0 + ch * 8);
      float4 f0 = *(const float4*)(Fc + bh * 1024 + j0 + ch * 8);
      float4 f1 = *(const float4*)(Fc + bh * 1024 + j0 + ch * 8 + 4);
      float vals[8];
      float tm = -1e30f;
#pragma unroll
      for (int e = 0; e < 8; ++e) {
        float fc = e < 4 ? ((const float*)&f0)[e] : ((const float*)&f1)[e - 4];
        float v = bf2f(sv[e]) * SM_SCALE - fc;
        if (jb == tb && ch * 8 + e > row64) v = -1e30f;
        vals[e] = v; tm = fmaxf(tm, v);
      }
      tm = fmaxf(tm, __shfl_xor(tm, 1));
      tm = fmaxf(tm, __shfl_xor(tm, 2));
      tm = fmaxf(tm, __shfl_xor(tm, 4));
      float mo = i ? m1 : m0;
      float mn = fmaxf(mo, tm);
      float s = __expf(mo - mn);
      u16x8 pv;
      float psum = 0.f;
#pragma unroll
      for (int e = 0; e < 8; ++e) {
        float p = __expf(vals[e] - mn);
        psum += p; pv[e] = f2bf(p);
      }
      int byt = ((row16 << 7) + (ch << 4)) ^ ((row16 & 7) << 4);
      *(u16x8*)((char*)Pl[w] + byt) = pv;
      psum += __shfl_xor(psum, 1);
      psum += __shfl_xor(psum, 2);
      psum += __shfl_xor(psum, 4);
      if (i) { m1 = mn; l1 = l1 * s + psum; } else { m0 = mn; l0 = l0 * s + psum; }
      sc[i] = s;
    }
    __builtin_amdgcn_wave_barrier();
    float cr[4];
#pragma unroll
    for (int r = 0; r < 4; ++r) {
      int rho = fq * 4 + r;
      int src = (rho & 7) * 8;
      float v0 = __shfl(sc[0], src);
      float v1 = __shfl(sc[1], src);
      cr[r] = (rho < 8) ? v0 : v1;
    }
#pragma unroll
    for (int c = 0; c < 4; ++c)
#pragma unroll
      for (int r = 0; r < 4; ++r) acc[c][r] *= cr[r];
#pragma unroll
    for (int kh = 0; kh < 2; ++kh) {
      s16x8 a = *(const s16x8*)((char*)Pl[w] + (((fr << 7) + (kh << 6) + (fq << 4)) ^ ((fr & 7) << 4)));
#pragma unroll
      for (int c = 0; c < 4; ++c) {
        s16x8 bb = *(const s16x8*)(VT + ((size_t)bh * 64 + 16 * c + fr) * 1024 + j0 + kh * 32 + fq * 8);
        acc[c] = __builtin_amdgcn_mfma_f32_16x16x32_bf16(a, bb, acc[c], 0, 0, 0);
      }
    }
    __builtin_amdgcn_wave_barrier();
  }
  float inv[4];
#pragma unroll
  for (int r = 0; r < 4; ++r) {
    int rho = fq * 4 + r;
    int src = (rho & 7) * 8;
    float v0 = __shfl(l0, src);
    float v1 = __shfl(l1, src);
    inv[r] = 1.f / ((rho < 8) ? v0 : v1);
  }
#pragma unroll
  for (int c = 0; c < 4; ++c) {
#pragma unroll
    for (int r = 0; r < 4; ++r) {
      int grow = t0 + 16 * w + fq * 4 + r;
      Ob[((size_t)(b * 1024) + grow) * 1024 + h * 64 + 16 * c + fr] = f2bf(acc[c][r] * inv[r]);
    }
  }
}

extern "C" void kernel_launch(void* const* d_in, const int* in_sizes, int n_in,
                              void* d_out, int out_size, void* d_ws, size_t ws_size,
                              hipStream_t stream) {
  const float* x    = (const float*)d_in[0];
  const float* Wq   = (const float*)d_in[1];
  const float* Wk   = (const float*)d_in[2];
  const float* Wv   = (const float*)d_in[3];
  const float* Wo   = (const float*)d_in[4];
  const float* Ww1  = (const float*)d_in[5];
  const float* Ww2  = (const float*)d_in[6];
  const float* Wb   = (const float*)d_in[7];
  const float* Wf   = (const float*)d_in[8];
  const float* delta= (const float*)d_in[9];

  char* ws = (char*)d_ws;
  unsigned short* xb   = (unsigned short*)(ws + OFF_XB);
  unsigned short* WqT  = (unsigned short*)(ws + OFF_WQT);
  unsigned short* WkT  = (unsigned short*)(ws + OFF_WKT);
  unsigned short* WvT  = (unsigned short*)(ws + OFF_WVT);
  unsigned short* WoT  = (unsigned short*)(ws + OFF_WOT);
  unsigned short* W1c  = (unsigned short*)(ws + OFF_W1C);
  unsigned short* W2T  = (unsigned short*)(ws + OFF_W2T);
  float*          Beta = (float*)(ws + OFF_BETA);
  unsigned short* Q16  = (unsigned short*)(ws + OFF_Q16);
  unsigned short* K16  = (unsigned short*)(ws + OFF_K16);
  unsigned short* VT   = (unsigned short*)(ws + OFF_VT);
  unsigned short* WN16 = (unsigned short*)(ws + OFF_WN16);
  unsigned short* WB16 = (unsigned short*)(ws + OFF_WB16);
  unsigned short* WNF16= (unsigned short*)(ws + OFF_WNF);
  unsigned short* ObB  = (unsigned short*)(ws + OFF_OB);
  unsigned short* BFT  = (unsigned short*)(ws + OFF_BFT);
  float*          Fc   = (float*)(ws + OFF_FC);
  unsigned short* Lbuf = (unsigned short*)(ws + OFF_L);
  unsigned short* Sbuf = (unsigned short*)(ws + OFF_L);
  unsigned short* CT   = (unsigned short*)(ws + OFF_CT);
  unsigned short* Gbuf = (unsigned short*)(ws + OFF_G);
  float*          BL   = (float*)(ws + OFF_BL);
  unsigned short* U128 = (unsigned short*)(ws + OFF_U128);
  unsigned short* B256 = (unsigned short*)(ws + OFF_B256);

  dim3 blk(256);
  // prep (all transposes + casts + BFT 128-row)
  prep_all<<<2160, blk, 0, stream>>>(Wq, Wk, Wv, Wo, Ww1, Ww2, x, Wb, Wf,
                                     WqT, WkT, WvT, WoT, W1c, W2T, xb, BFT);
  // WfusedT = W2T @ W1c^T (rank-64 fold; lives in WN16 region until wnorm2)
  gemm_nt<0><<<dim3(16,16), blk, 0, stream>>>(W2T, W1c, WN16, 1024, 1024, 64);
  // Q, K, VT, WNF, BL in one 264-block launch (256x128 tiles, 1 round)
  proj_big<<<264, blk, 0, stream>>>(xb, WqT, WkT, WvT, WN16, BFT,
                                    Q16, K16, VT, WNF16, BL);
  // beta/logsigmoid/cumsum fused
  bgfc<<<32, blk, 0, stream>>>(BL, delta, Beta, Fc);
  wnorm2<<<2048, blk, 0, stream>>>(WNF16, Beta, WN16, WB16);
  // L and G (both stored NEGATED)
  pairLG<<<dim3(36 * 32), blk, 0, stream>>>(WN16, Q16, WB16, Lbuf, Gbuf);
  // triangular solve: fused inverses -> 256 off-diag piece -> 4 band steps
  invbuild<<<dim3(8,32), blk, 0, stream>>>(Lbuf, U128);
  u256build<<<dim3(4,32), blk, 0, stream>>>(Lbuf, U128, B256);
  for (int ib = 0; ib < 4; ++ib)
    solve256<<<dim3(2 * ib + 2, 32), blk, 0, stream>>>(WN16, K16, Lbuf, U128, B256, CT, ib);
  // S = QK^T + Gneg C (sorted band grid; reuses L region; pipelined)
  score128s<<<dim3(36 * 32), blk, 0, stream>>>(Q16, K16, Gbuf, CT, Sbuf);
  // online softmax + PV (wave-independent)
  pv_kernel<<<dim3(512), blk, 0, stream>>>(Sbuf, VT, Fc, ObB);
  // output projection (f32 out; XCD-grouped, pipelined)
  gemm_outproj<<<512, blk, 0, stream>>>(ObB, WoT, (float*)d_out);
}

// Round 15
// 281.782 us; speedup vs baseline: 1.0905x; 1.0905x over previous
//
#include <hip/hip_runtime.h>
#include <hip/hip_bf16.h>

#define DEV static __device__ __forceinline__

constexpr float SM_SCALE = 0.125f;   // hd^-0.5, hd=64

typedef __attribute__((ext_vector_type(8))) short s16x8;
typedef __attribute__((ext_vector_type(8))) unsigned short u16x8;
typedef __attribute__((ext_vector_type(4))) unsigned short u16x4;
typedef __attribute__((ext_vector_type(4))) float f32x4;

DEV float bf2f(unsigned short u) {
  union { unsigned int i; float f; } v; v.i = ((unsigned int)u) << 16; return v.f;
}
DEV unsigned short f2bf(float f) {
  union { float f; unsigned int i; } v; v.f = f;
  unsigned int r = v.i + 0x7fffu + ((v.i >> 16) & 1u);
  return (unsigned short)(r >> 16);
}
DEV void tri_unrank(int r, int& k, int& i) {
  k = (int)((sqrtf(8.f * r + 1.f) - 1.f) * 0.5f);
  while (k * (k + 1) / 2 > r) --k;
  while ((k + 1) * (k + 2) / 2 <= r) ++k;
  i = r - k * (k + 1) / 2;
}
// async global->LDS, 16B per lane; dest must be wave-linear (base + lane*16)
DEV void glds16(const void* g, void* l) {
  __builtin_amdgcn_global_load_lds(
      (const __attribute__((address_space(1))) void*)g,
      (__attribute__((address_space(3))) void*)l, 16, 0, 0);
}
DEV void pipe_drain_barrier() {
  asm volatile("s_waitcnt vmcnt(0)" ::: "memory");
  __builtin_amdgcn_s_barrier();
}

// ---------- workspace layout (bytes) ----------
constexpr size_t OFF_XB   = 0;                       // 4MB xb bf16 [2048][1024]
constexpr size_t OFF_WQT  = 4194304;                 // 2MB
constexpr size_t OFF_WKT  = 6291456;                 // 2MB
constexpr size_t OFF_WVT  = 8388608;
constexpr size_t OFF_WOT  = 10485760;
constexpr size_t OFF_W1C  = 12582912;                // 128KB bf16 Ww1 cast (1024x64)
constexpr size_t OFF_W2T  = 12713984;                // 128KB
constexpr size_t OFF_BETA = 12582912;                // reuse W1C after wfuse
constexpr size_t OFF_Q16  = 12845056;                // 4MB bf16 2048x1024
constexpr size_t OFF_K16  = 17039360;                // 4MB
constexpr size_t OFF_VT   = 21233664;                // 4MB  VT[b][64h*d][1024n]
constexpr size_t OFF_WN16 = 25427968;                // 4MB; holds WfusedT until wnorm2
constexpr size_t OFF_WB16 = 29622272;                // 4MB
constexpr size_t OFF_WNF  = 33816576;                // 4MB (reused as Ob)
constexpr size_t OFF_OB   = 33816576;
constexpr size_t OFF_BFT  = 38010880;                // 256KB bf16 (128x1024)
constexpr size_t OFF_FC   = 38273024;                // 128KB
constexpr size_t OFF_L    = 38404096;                // 64MB, stores -L (reused as S)
constexpr size_t OFF_CT   = 105512960;               // 64MB
constexpr size_t OFF_G    = 172621824;               // 64MB, stores -G
constexpr size_t OFF_BL   = 239730688;               // 512KB f32 2048x64
constexpr size_t OFF_U128 = 244187136;               // 8MB bf16 [32][8][128][128]
constexpr size_t OFF_B256 = 252575744;               // 4MB bf16 [32][4][128][128]

// ================= fused prep: transposes + casts + BFT(128 rows); grid 2160 =================
__global__ __launch_bounds__(256) void prep_all(
    const float* __restrict__ W0, const float* __restrict__ W1,
    const float* __restrict__ W2, const float* __restrict__ W3,
    const float* __restrict__ Ww1, const float* __restrict__ Ww2,
    const float* __restrict__ x, const float* __restrict__ Wb,
    const float* __restrict__ Wf,
    unsigned short* __restrict__ D0, unsigned short* __restrict__ D1,
    unsigned short* __restrict__ D2, unsigned short* __restrict__ D3,
    unsigned short* __restrict__ W1c, unsigned short* __restrict__ W2T,
    unsigned short* __restrict__ xb, unsigned short* __restrict__ BFT) {
  int bidx = blockIdx.x;
  int t = threadIdx.x;
  if (bidx >= 2096) {                      // BFT build (64 blocks, 128x1024)
    int e0 = ((bidx - 2096) * 256 + t) * 8;
    int j = e0 >> 10, i0 = e0 & 1023;
    u16x8 o;
#pragma unroll
    for (int e = 0; e < 8; ++e) {
      int i = i0 + e;
      float v = 0.f;
      if (j < 16) v = Wb[i * 16 + j];
      else if (j < 32) v = Wf[i * 16 + (j - 16)];
      o[e] = f2bf(v);
    }
    *(u16x8*)(BFT + e0) = o;
    return;
  }
  if (bidx >= 2064) {                      // W1 cast (32 blocks)
    int i = ((bidx - 2064) * 256 + t) * 8;
    float4 a = *(const float4*)(Ww1 + i);
    float4 b = *(const float4*)(Ww1 + i + 4);
    u16x8 o;
    o[0] = f2bf(a.x); o[1] = f2bf(a.y); o[2] = f2bf(a.z); o[3] = f2bf(a.w);
    o[4] = f2bf(b.x); o[5] = f2bf(b.y); o[6] = f2bf(b.z); o[7] = f2bf(b.w);
    *(u16x8*)(W1c + i) = o;
    return;
  }
  if (bidx >= 1040) {                      // x cast (1024 blocks)
    int i = ((bidx - 1040) * 256 + t) * 8;
    float4 a = *(const float4*)(x + i);
    float4 b = *(const float4*)(x + i + 4);
    u16x8 o;
    o[0] = f2bf(a.x); o[1] = f2bf(a.y); o[2] = f2bf(a.z); o[3] = f2bf(a.w);
    o[4] = f2bf(b.x); o[5] = f2bf(b.y); o[6] = f2bf(b.z); o[7] = f2bf(b.w);
    *(u16x8*)(xb + i) = o;
    return;
  }
  const float* src; unsigned short* dst; int R, C, c0, r0;
  if (bidx >= 1024) {                      // W2T transpose (16 blocks)
    src = Ww2; dst = W2T; R = 64; C = 1024;
    c0 = (bidx - 1024) * 64; r0 = 0;
  } else {
    int z = bidx >> 8, xy = bidx & 255;
    src = z == 0 ? W0 : z == 1 ? W1 : z == 2 ? W2 : W3;
    dst = z == 0 ? D0 : z == 1 ? D1 : z == 2 ? D2 : D3;
    R = 1024; C = 1024;
    c0 = (xy & 15) * 64; r0 = (xy >> 4) * 64;
  }
  __shared__ float tile[64 * 65];
#pragma unroll
  for (int i = 0; i < 16; ++i) {
    int lin = t + i * 256; int r = lin >> 6, c = lin & 63;
    tile[r * 65 + c] = src[(size_t)(r0 + r) * C + c0 + c];
  }
  __syncthreads();
#pragma unroll
  for (int i = 0; i < 16; ++i) {
    int lin = t + i * 256; int c = lin >> 6, r = lin & 63;
    dst[(size_t)(c0 + c) * R + r0 + r] = f2bf(tile[r * 65 + c]);
  }
}

// beta + log_sigmoid + cumsum fused; grid 32 (bh)
__global__ __launch_bounds__(256) void bgfc(const float* __restrict__ BL,
    const float* __restrict__ delta, float* __restrict__ Beta, float* __restrict__ Fc) {
  int bh = blockIdx.x;
  int b = bh >> 4, h = bh & 15;
  int t = threadIdx.x;
  __shared__ float buf[1024];
  __shared__ float tsum[256];
  float dh = delta[h];
#pragma unroll
  for (int i = 0; i < 4; ++i) {
    int n = t + i * 256;
    int row = (b << 10) + n;
    float braw = BL[row * 64 + h];
    Beta[row * 16 + h] = 2.f / (1.f + __expf(-braw));
    float lraw = BL[row * 64 + 16 + h] + dh;
    buf[n] = (lraw >= 0.f) ? -log1pf(__expf(-lraw)) : (lraw - log1pf(__expf(lraw)));
  }
  __syncthreads();
  float loc[4]; float run = 0.f;
#pragma unroll
  for (int i = 0; i < 4; ++i) { run += buf[t * 4 + i]; loc[i] = run; }
  tsum[t] = run;
  __syncthreads();
  for (int off = 1; off < 256; off <<= 1) {
    float add = (t >= off) ? tsum[t - off] : 0.f;
    __syncthreads();
    tsum[t] += add;
    __syncthreads();
  }
  float excl = tsum[t] - run;
#pragma unroll
  for (int i = 0; i < 4; ++i) Fc[bh * 1024 + t * 4 + i] = excl + loc[i];
}

// ================= wfuse + BL: 288 blocks (256 WfusedT tiles + 32 BL tiles) =================
__global__ __launch_bounds__(256) void wfuse_bl(
    const unsigned short* __restrict__ W2T, const unsigned short* __restrict__ W1c,
    const unsigned short* __restrict__ xb, const unsigned short* __restrict__ BFT,
    unsigned short* __restrict__ WF, float* __restrict__ BL) {
  int v = blockIdx.x;
  const unsigned short *A, *BT; int m0, n0, K, mode;
  if (v < 256) { A = W2T; BT = W1c; m0 = (v >> 4) * 64; n0 = (v & 15) * 64; K = 64; mode = 0; }
  else { A = xb; BT = BFT; m0 = (v - 256) * 64; n0 = 0; K = 1024; mode = 1; }
  __shared__ unsigned short As[2 * 4096];
  __shared__ unsigned short Bs[2 * 4096];
  int t = threadIdx.x;
  int w = t >> 6, l = t & 63, fr = l & 15;
  int koB = (l >> 4) * 16;
  f32x4 acc[4];
#pragma unroll
  for (int c = 0; c < 4; ++c) acc[c] = (f32x4){0.f, 0.f, 0.f, 0.f};

#define STAGE_W(buf, k0) {                                              \
  _Pragma("unroll")                                                     \
  for (int i = 0; i < 2; ++i) {                                         \
    int cid = t + i * 256;                                              \
    int row = cid >> 3, ch = cid & 7;                                   \
    int chs = ch ^ (row & 7);                                           \
    glds16(A + (size_t)(m0 + row) * K + (k0) + chs * 8, (char*)(As + (buf) * 4096) + cid * 16); \
    glds16(BT + (size_t)(n0 + row) * K + (k0) + chs * 8, (char*)(Bs + (buf) * 4096) + cid * 16); \
  } }

  int nt = K >> 6;
  STAGE_W(0, 0);
  pipe_drain_barrier();
  int cur = 0;
  for (int kt = 0; kt < nt; ++kt) {
    if (kt + 1 < nt) STAGE_W(cur ^ 1, (kt + 1) * 64);
    const char* Ab = (const char*)(As + cur * 4096);
    const char* Bb = (const char*)(Bs + cur * 4096);
    __builtin_amdgcn_s_setprio(1);
#pragma unroll
    for (int kh = 0; kh < 2; ++kh) {
      int ra = 16 * w + fr;
      s16x8 a = *(const s16x8*)(Ab + (((ra << 7) + (kh << 6) + koB) ^ ((ra & 7) << 4)));
#pragma unroll
      for (int c = 0; c < 4; ++c) {
        int rb = 16 * c + fr;
        s16x8 bb = *(const s16x8*)(Bb + (((rb << 7) + (kh << 6) + koB) ^ ((rb & 7) << 4)));
        acc[c] = __builtin_amdgcn_mfma_f32_16x16x32_bf16(a, bb, acc[c], 0, 0, 0);
      }
    }
    __builtin_amdgcn_s_setprio(0);
    pipe_drain_barrier();
    cur ^= 1;
  }
#undef STAGE_W
  int rbase = m0 + 16 * w + ((l >> 4) << 2);
#pragma unroll
  for (int c = 0; c < 4; ++c) {
    int col = n0 + 16 * c + fr;
#pragma unroll
    for (int r = 0; r < 4; ++r) {
      if (mode == 0) WF[(size_t)(rbase + r) * 1024 + col] = f2bf(acc[c][r]);
      else BL[(size_t)(rbase + r) * 64 + col] = acc[c][r];
    }
  }
}

// ================= mega projection: Q,K + VT + WNF; XCD-grouped 512 blocks =================
__global__ __launch_bounds__(256) void proj_big(const unsigned short* __restrict__ xb,
    const unsigned short* __restrict__ WqT, const unsigned short* __restrict__ WkT,
    const unsigned short* __restrict__ WvT, const unsigned short* __restrict__ WfT,
    unsigned short* __restrict__ Q16, unsigned short* __restrict__ K16,
    unsigned short* __restrict__ VT, unsigned short* __restrict__ WNF) {
  int sg = blockIdx.x;                       // 512 = 8 * 64 exactly
  int virt = (sg % 8) * 64 + (sg / 8);       // bijective chunked XCD swizzle
  const unsigned short *A, *BT; unsigned short* out; int m0, n0;
  if (virt < 256) {                          // Q/K: 16my x 16nx in 4x4 groups, 2x2 supergroups
    int g = virt >> 4, in = virt & 15;
    int ssb = g >> 2, gin = g & 3;
    int mb = (ssb >> 1) * 2 + (gin >> 1);
    int nb = (ssb & 1) * 2 + (gin & 1);
    int my = mb * 4 + (in >> 2);
    int nx = nb * 4 + (in & 3);
    m0 = my * 128; A = xb;
    if (nx < 8) { BT = WqT; out = Q16; n0 = nx * 128; }
    else { BT = WkT; out = K16; n0 = (nx - 8) * 128; }
  } else if (virt < 384) {                   // VT: per batch 8x8 in 4x4 groups
    int r = virt - 256; int bz = r >> 6; int rr = r & 63;
    int g = rr >> 4, in = rr & 15;
    int my = (g >> 1) * 4 + (in >> 2);
    int nx = (g & 1) * 4 + (in & 3);
    m0 = my * 128; n0 = nx * 128;
    A = WvT; BT = xb + ((size_t)bz << 20); out = VT + ((size_t)bz << 20);
  } else {                                   // WNF: 16my x 8nx in 4x4 groups
    int r = virt - 384;
    int g = r >> 4, in = r & 15;
    int my = (g >> 1) * 4 + (in >> 2);
    int nx = (g & 1) * 4 + (in & 3);
    m0 = my * 128; n0 = nx * 128;
    A = xb; BT = WfT; out = WNF;
  }
  int t = threadIdx.x;
  int w = t >> 6, l = t & 63;
  int wr = w >> 1, wc = w & 1;
  int fr = l & 15, fq = l >> 4;
  __shared__ unsigned short As[2 * 8192];
  __shared__ unsigned short Bs[2 * 8192];
  f32x4 acc[4][4];
#pragma unroll
  for (int m = 0; m < 4; ++m)
#pragma unroll
    for (int c = 0; c < 4; ++c) acc[m][c] = (f32x4){0.f, 0.f, 0.f, 0.f};

#define STAGE_PB(buf, k0) {                                             \
  _Pragma("unroll")                                                     \
  for (int i = 0; i < 4; ++i) {                                         \
    int cid = t + i * 256;                                              \
    int row = cid >> 3, ch = cid & 7;                                   \
    int chs = ch ^ (row & 7);                                           \
    glds16(A + (size_t)(m0 + row) * 1024 + (k0) + chs * 8, (char*)(As + (buf) * 8192) + cid * 16); \
    glds16(BT + (size_t)(n0 + row) * 1024 + (k0) + chs * 8, (char*)(Bs + (buf) * 8192) + cid * 16); \
  } }

  STAGE_PB(0, 0);
  pipe_drain_barrier();
  int cur = 0;
  for (int kt = 0; kt < 16; ++kt) {
    if (kt < 15) STAGE_PB(cur ^ 1, (kt + 1) * 64);
    const char* Ab = (const char*)(As + cur * 8192);
    const char* Bb = (const char*)(Bs + cur * 8192);
    __builtin_amdgcn_s_setprio(1);
#pragma unroll
    for (int kh = 0; kh < 2; ++kh) {
      s16x8 af[4], bfv[4];
#pragma unroll
      for (int m = 0; m < 4; ++m) {
        int ra = wr * 64 + 16 * m + fr;
        af[m] = *(const s16x8*)(Ab + (((ra << 7) + (kh << 6) + (fq << 4)) ^ ((ra & 7) << 4)));
      }
#pragma unroll
      for (int c = 0; c < 4; ++c) {
        int rb = wc * 64 + 16 * c + fr;
        bfv[c] = *(const s16x8*)(Bb + (((rb << 7) + (kh << 6) + (fq << 4)) ^ ((rb & 7) << 4)));
      }
#pragma unroll
      for (int m = 0; m < 4; ++m)
#pragma unroll
        for (int c = 0; c < 4; ++c)
          acc[m][c] = __builtin_amdgcn_mfma_f32_16x16x32_bf16(af[m], bfv[c], acc[m][c], 0, 0, 0);
    }
    __builtin_amdgcn_s_setprio(0);
    pipe_drain_barrier();
    cur ^= 1;
  }
#undef STAGE_PB
#pragma unroll
  for (int m = 0; m < 4; ++m) {
#pragma unroll
    for (int c = 0; c < 4; ++c) {
      int col = n0 + wc * 64 + 16 * c + fr;
#pragma unroll
      for (int r = 0; r < 4; ++r) {
        int grow = m0 + wr * 64 + 16 * m + fq * 4 + r;
        out[(size_t)grow * 1024 + col] = f2bf(acc[m][c][r]);
      }
    }
  }
}

// ================= output projection: 64-tile, XCD-grouped 512 blocks, f32 out =================
__global__ __launch_bounds__(256) void gemm_outproj(const unsigned short* __restrict__ A,
    const unsigned short* __restrict__ BT, float* __restrict__ out) {
  int sg = blockIdx.x;                       // 512 = 8 * 64 exactly
  int virt = (sg & 7) * 64 + (sg >> 3);      // each XCD: one 8x8 panel group (2MB WS)
  int g = virt >> 6, in = virt & 63;
  int my = (g >> 1) * 8 + (in >> 3);         // 0..31
  int nx = (g & 1) * 8 + (in & 7);           // 0..15
  int m0 = my * 64, n0 = nx * 64;
  const int K = 1024, N = 1024;
  __shared__ unsigned short As[2 * 4096];
  __shared__ unsigned short Bs[2 * 4096];
  int t = threadIdx.x;
  int w = t >> 6, l = t & 63, fr = l & 15;
  int koB = (l >> 4) * 16;
  f32x4 acc[4];
#pragma unroll
  for (int c = 0; c < 4; ++c) acc[c] = (f32x4){0.f, 0.f, 0.f, 0.f};

#define STAGE_O(buf, k0) {                                              \
  _Pragma("unroll")                                                     \
  for (int i = 0; i < 2; ++i) {                                         \
    int cid = t + i * 256;                                              \
    int row = cid >> 3, ch = cid & 7;                                   \
    int chs = ch ^ (row & 7);                                           \
    glds16(A + (size_t)(m0 + row) * K + (k0) + chs * 8, (char*)(As + (buf) * 4096) + cid * 16); \
    glds16(BT + (size_t)(n0 + row) * K + (k0) + chs * 8, (char*)(Bs + (buf) * 4096) + cid * 16); \
  } }

  STAGE_O(0, 0);
  pipe_drain_barrier();
  int cur = 0;
  for (int kt = 0; kt < 16; ++kt) {
    if (kt + 1 < 16) STAGE_O(cur ^ 1, (kt + 1) * 64);
    const char* Ab = (const char*)(As + cur * 4096);
    const char* Bb = (const char*)(Bs + cur * 4096);
    __builtin_amdgcn_s_setprio(1);
#pragma unroll
    for (int kh = 0; kh < 2; ++kh) {
      int ra = 16 * w + fr;
      s16x8 a = *(const s16x8*)(Ab + (((ra << 7) + (kh << 6) + koB) ^ ((ra & 7) << 4)));
#pragma unroll
      for (int c = 0; c < 4; ++c) {
        int rb = 16 * c + fr;
        s16x8 bb = *(const s16x8*)(Bb + (((rb << 7) + (kh << 6) + koB) ^ ((rb & 7) << 4)));
        acc[c] = __builtin_amdgcn_mfma_f32_16x16x32_bf16(a, bb, acc[c], 0, 0, 0);
      }
    }
    __builtin_amdgcn_s_setprio(0);
    pipe_drain_barrier();
    cur ^= 1;
  }
#undef STAGE_O
  int rbase = m0 + 16 * w + ((l >> 4) << 2);
#pragma unroll
  for (int c = 0; c < 4; ++c) {
    int col = n0 + 16 * c + fr;
#pragma unroll
    for (int r = 0; r < 4; ++r)
      out[(size_t)(rbase + r) * N + col] = acc[c][r];
  }
}

// ================= w normalize + beta-scale =================
__global__ __launch_bounds__(256) void wnorm2(const unsigned short* __restrict__ WNF,
    const float* __restrict__ Beta, unsigned short* __restrict__ WN,
    unsigned short* __restrict__ WB) {
  int row = blockIdx.x;
  int wave = threadIdx.x >> 6, lane = threadIdx.x & 63;
#pragma unroll
  for (int i = 0; i < 4; ++i) {
    int hh = wave * 4 + i;
    size_t idx = ((size_t)row << 10) + hh * 64 + lane;
    float v = bf2f(WNF[idx]);
    float ss = v * v;
#pragma unroll
    for (int off = 1; off < 64; off <<= 1) ss += __shfl_xor(ss, off);
    float wn = v * rsqrtf(ss + 1e-6f);
    WN[idx] = f2bf(wn);
    WB[idx] = f2bf(wn * Beta[row * 16 + hh]);
  }
}

// ================= pair fused: writes NEGATED L and G =================
__global__ __launch_bounds__(256) void pairLG(const unsigned short* __restrict__ WN,
    const unsigned short* __restrict__ Q, const unsigned short* __restrict__ WB,
    unsigned short* __restrict__ Lg, unsigned short* __restrict__ Gg) {
  int idx = blockIdx.x;
  int bh = idx & 31, r0r = idx >> 5;
  int tb2, jb2; tri_unrank(r0r, tb2, jb2);
  int b = bh >> 4, h = bh & 15;
  int m0 = tb2 * 128, n0 = jb2 * 128;
  int t = threadIdx.x;
  int w = t >> 6, l = t & 63;
  int wr = w >> 1, wc = w & 1;
  int fr = l & 15, fq = l >> 4;
  __shared__ unsigned short As[128 * 64];
  __shared__ unsigned short Bs[128 * 64];
  const unsigned short* WNb = WN + ((size_t)b << 20) + h * 64;
  const unsigned short* Qb  = Q + ((size_t)b << 20) + h * 64;
  const unsigned short* WBb = WB + ((size_t)b << 20) + h * 64;
  size_t base = (size_t)bh << 20;
#pragma unroll
  for (int i = 0; i < 4; ++i) {
    int cid = t + i * 256;
    int row = cid >> 3, ch = cid & 7;
    int chs = ch ^ (row & 7);
    glds16(WNb + ((size_t)(m0 + row) << 10) + chs * 8, (char*)As + cid * 16);
    glds16(WBb + ((size_t)(n0 + row) << 10) + chs * 8, (char*)Bs + cid * 16);
  }
  __syncthreads();
  for (int pass = 0; pass < 2; ++pass) {
    f32x4 acc[4][4];
#pragma unroll
    for (int m = 0; m < 4; ++m)
#pragma unroll
      for (int c = 0; c < 4; ++c) acc[m][c] = (f32x4){0.f, 0.f, 0.f, 0.f};
#pragma unroll
    for (int kh = 0; kh < 2; ++kh) {
      s16x8 af[4], bfv[4];
#pragma unroll
      for (int m = 0; m < 4; ++m) {
        int ra = wr * 64 + 16 * m + fr;
        af[m] = *(const s16x8*)((char*)As + (((ra << 7) + (kh << 6) + (fq << 4)) ^ ((ra & 7) << 4)));
      }
#pragma unroll
      for (int c = 0; c < 4; ++c) {
        int rb = wc * 64 + 16 * c + fr;
        bfv[c] = *(const s16x8*)((char*)Bs + (((rb << 7) + (kh << 6) + (fq << 4)) ^ ((rb & 7) << 4)));
      }
#pragma unroll
      for (int m = 0; m < 4; ++m)
#pragma unroll
        for (int c = 0; c < 4; ++c)
          acc[m][c] = __builtin_amdgcn_mfma_f32_16x16x32_bf16(af[m], bfv[c], acc[m][c], 0, 0, 0);
    }
    unsigned short* dst = pass ? Gg : Lg;
#pragma unroll
    for (int m = 0; m < 4; ++m) {
#pragma unroll
      for (int c = 0; c < 4; ++c) {
        int gj = n0 + wc * 64 + 16 * c + fr;
#pragma unroll
        for (int r = 0; r < 4; ++r) {
          int gi = m0 + wr * 64 + 16 * m + fq * 4 + r;
          bool keep = pass ? (gj <= gi) : (gj < gi);
          dst[base + ((size_t)gi << 10) + gj] = f2bf(keep ? -acc[m][c][r] : 0.f);
        }
      }
    }
    if (pass == 0) {
      __syncthreads();
#pragma unroll
      for (int i = 0; i < 4; ++i) {
        int cid = t + i * 256;
        int row = cid >> 3, ch = cid & 7;
        int chs = ch ^ (row & 7);
        glds16(Qb + ((size_t)(m0 + row) << 10) + chs * 8, (char*)As + cid * 16);
      }
      __syncthreads();
    }
  }
}

// ================= score: S = Q K^T + Gneg @ C, sorted 1D grid; 2-phase pipeline =================
__global__ __launch_bounds__(256) void score128s(const unsigned short* __restrict__ Q,
    const unsigned short* __restrict__ Kk, const unsigned short* __restrict__ G,
    const unsigned short* __restrict__ CT, unsigned short* __restrict__ Sg) {
  int idx = blockIdx.x;
  int bh = idx & 31, r0r = idx >> 5;
  int k, i; tri_unrank(r0r, k, i);
  int tb2 = (7 - k) + i, jb2 = i;
  int b = bh >> 4, h = bh & 15;
  int m0 = tb2 * 128, n0 = jb2 * 128;
  int t = threadIdx.x;
  int w = t >> 6, l = t & 63;
  int wr = w >> 1, wc = w & 1;
  int fr = l & 15, fq = l >> 4;
  __shared__ unsigned short As[2 * 8192];
  __shared__ unsigned short Bs[2 * 8192];
  size_t base = (size_t)bh << 20;
  const unsigned short* Qb_ = Q + ((size_t)b << 20) + h * 64;
  const unsigned short* Kb_ = Kk + ((size_t)b << 20) + h * 64;
  const unsigned short* Gb_ = G + base;
  const unsigned short* Cb_ = CT + base;
  int kbase = jb2 * 128;
  int nsteps = 1 + (tb2 - jb2 + 1) * 2;
  f32x4 acc[4][4];
#pragma unroll
  for (int m = 0; m < 4; ++m)
#pragma unroll
    for (int c = 0; c < 4; ++c) acc[m][c] = (f32x4){0.f, 0.f, 0.f, 0.f};

#define STAGE_SC(buf, stp) {                                            \
  const unsigned short* pa; const unsigned short* pb; int koff;         \
  if ((stp) == 0) { pa = Qb_; pb = Kb_; koff = 0; }                     \
  else { pa = Gb_; pb = Cb_; koff = kbase + ((stp) - 1) * 64; }         \
  _Pragma("unroll")                                                     \
  for (int i2 = 0; i2 < 4; ++i2) {                                      \
    int cid = t + i2 * 256;                                             \
    int row = cid >> 3, ch = cid & 7;                                   \
    int chs = ch ^ (row & 7);                                           \
    glds16(pa + ((size_t)(m0 + row) << 10) + koff + chs * 8, (char*)(As + (buf) * 8192) + cid * 16); \
    glds16(pb + ((size_t)(n0 + row) << 10) + koff + chs * 8, (char*)(Bs + (buf) * 8192) + cid * 16); \
  } }

  STAGE_SC(0, 0);
  pipe_drain_barrier();
  int cur = 0;
  for (int step = 0; step < nsteps; ++step) {
    if (step + 1 < nsteps) STAGE_SC(cur ^ 1, step + 1);
    const char* Ab = (const char*)(As + cur * 8192);
    const char* Bb = (const char*)(Bs + cur * 8192);
    __builtin_amdgcn_s_setprio(1);
#pragma unroll
    for (int kh = 0; kh < 2; ++kh) {
      s16x8 af[4], bfv[4];
#pragma unroll
      for (int m = 0; m < 4; ++m) {
        int ra = wr * 64 + 16 * m + fr;
        af[m] = *(const s16x8*)(Ab + (((ra << 7) + (kh << 6) + (fq << 4)) ^ ((ra & 7) << 4)));
      }
#pragma unroll
      for (int c = 0; c < 4; ++c) {
        int rb = wc * 64 + 16 * c + fr;
        bfv[c] = *(const s16x8*)(Bb + (((rb << 7) + (kh << 6) + (fq << 4)) ^ ((rb & 7) << 4)));
      }
#pragma unroll
      for (int m = 0; m < 4; ++m)
#pragma unroll
        for (int c = 0; c < 4; ++c)
          acc[m][c] = __builtin_amdgcn_mfma_f32_16x16x32_bf16(af[m], bfv[c], acc[m][c], 0, 0, 0);
    }
    __builtin_amdgcn_s_setprio(0);
    pipe_drain_barrier();
    cur ^= 1;
  }
#undef STAGE_SC
#pragma unroll
  for (int m = 0; m < 4; ++m) {
#pragma unroll
    for (int c = 0; c < 4; ++c) {
      int gj = n0 + wc * 64 + 16 * c + fr;
#pragma unroll
      for (int r = 0; r < 4; ++r) {
        int gi = m0 + wr * 64 + 16 * m + fq * 4 + r;
        Sg[base + ((size_t)gi << 10) + gj] = f2bf(acc[m][c][r]);
      }
    }
  }
}

// ================= invbuild: 2x inv64 + U128 assembly in one block; grid (8,32) =================
__global__ __launch_bounds__(256) void invbuild(const unsigned short* __restrict__ Lb,
    unsigned short* __restrict__ U128) {
  int ib = blockIdx.x, bh = blockIdx.y;
  int t = threadIdx.x, w = t >> 6, l = t & 63, fr = l & 15, fq = l >> 4;
  int s0 = ib * 128;
  size_t base = (size_t)bh << 20;
  unsigned short* Uo = U128 + (((size_t)(bh * 8 + ib)) << 14);
  __shared__ float LD[2][64 * 65];
  __shared__ unsigned short UaR[64 * 72];
  __shared__ unsigned short UcR[64 * 72];
  __shared__ unsigned short UaT[64 * 64];
  __shared__ unsigned short T1T[64 * 64];
#pragma unroll
  for (int i = 0; i < 32; ++i) {
    int lin = t + i * 256;
    int blk = lin >> 12, s = (lin >> 6) & 63, r = lin & 63;
    LD[blk][s * 65 + r] = -bf2f(Lb[base + ((size_t)(s0 + blk * 64 + s) << 10) + s0 + blk * 64 + r]);
  }
  __syncthreads();
  if (t < 128) {
    int blk = t >> 6, j = t & 63;
    const float* ld = LD[blk];
    float cc[64];
#pragma unroll
    for (int s = 0; s < 64; ++s) cc[s] = (s == j) ? 1.f : 0.f;
#pragma unroll
    for (int r = 0; r < 63; ++r) {
      float val = cc[r];
#pragma unroll
      for (int s = r + 1; s < 64; ++s) cc[s] -= ld[s * 65 + r] * val;
    }
    if (blk == 0) {
#pragma unroll
      for (int s = 0; s < 64; ++s) {
        unsigned short v = f2bf(cc[s]);
        UaR[s * 72 + j] = v;
        *(unsigned short*)((char*)UaT + (((j << 7) + (s << 1)) ^ ((j & 7) << 4))) = v;
      }
    } else {
#pragma unroll
      for (int s = 0; s < 64; ++s) UcR[s * 72 + j] = f2bf(cc[s]);
    }
  }
  __syncthreads();
#pragma unroll
  for (int i = 0; i < 8; ++i) {
    int cid = t + i * 256;
    int row = cid >> 4, ch = cid & 15;
    u16x8 v = {0, 0, 0, 0, 0, 0, 0, 0};
    if (row < 64) {
      if (ch < 8) {
#pragma unroll
        for (int e = 0; e < 8; ++e) v[e] = UaR[row * 72 + ch * 8 + e];
      }
      *(u16x8*)(Uo + row * 128 + ch * 8) = v;
    } else if (ch >= 8) {
#pragma unroll
      for (int e = 0; e < 8; ++e) v[e] = UcR[(row - 64) * 72 + (ch - 8) * 8 + e];
      *(u16x8*)(Uo + row * 128 + ch * 8) = v;
    }
  }
  f32x4 a1[4];
#pragma unroll
  for (int c = 0; c < 4; ++c) a1[c] = (f32x4){0.f, 0.f, 0.f, 0.f};
#pragma unroll
  for (int kc = 0; kc < 2; ++kc) {
    s16x8 af = *(const s16x8*)(Lb + base + ((size_t)(s0 + 64 + 16 * w + fr) << 10) + s0 + kc * 32 + fq * 8);
#pragma unroll
    for (int c = 0; c < 4; ++c) {
      int j = 16 * c + fr;
      s16x8 bb = *(const s16x8*)((char*)UaT + (((j << 7) + (kc << 6) + (fq << 4)) ^ ((j & 7) << 4)));
      a1[c] = __builtin_amdgcn_mfma_f32_16x16x32_bf16(af, bb, a1[c], 0, 0, 0);
    }
  }
#pragma unroll
  for (int c = 0; c < 4; ++c) {
    int gj = 16 * c + fr;
    int sb = 16 * w + fq * 4;
    u16x4 pk;
#pragma unroll
    for (int r = 0; r < 4; ++r) pk[r] = f2bf(a1[c][r]);
    *(u16x4*)((char*)T1T + (((gj << 7) + (sb << 1)) ^ ((gj & 7) << 4))) = pk;
  }
  __syncthreads();
  f32x4 a2[4];
#pragma unroll
  for (int c = 0; c < 4; ++c) a2[c] = (f32x4){0.f, 0.f, 0.f, 0.f};
#pragma unroll
  for (int kc = 0; kc < 2; ++kc) {
    s16x8 af = *(const s16x8*)(UcR + (16 * w + fr) * 72 + kc * 32 + fq * 8);
#pragma unroll
    for (int c = 0; c < 4; ++c) {
      int j = 16 * c + fr;
      s16x8 bb = *(const s16x8*)((char*)T1T + (((j << 7) + (kc << 6) + (fq << 4)) ^ ((j & 7) << 4)));
      a2[c] = __builtin_amdgcn_mfma_f32_16x16x32_bf16(af, bb, a2[c], 0, 0, 0);
    }
  }
#pragma unroll
  for (int c = 0; c < 4; ++c) {
    int gj = 16 * c + fr;
#pragma unroll
    for (int r = 0; r < 4; ++r)
      Uo[(64 + 16 * w + fq * 4 + r) * 128 + gj] = f2bf(a2[c][r]);
  }
}

// ================= u256build: B256 = Uc128 @ (Lneg_BA @ Ua128); grid (4,32) =================
__global__ __launch_bounds__(256) void u256build(const unsigned short* __restrict__ Lb,
    const unsigned short* __restrict__ U128, unsigned short* __restrict__ B256) {
  int qb = blockIdx.x, bh = blockIdx.y;
  int t = threadIdx.x, w = t >> 6, l = t & 63, fr = l & 15, fq = l >> 4;
  int s0 = qb * 256;
  size_t base = (size_t)bh << 20;
  const unsigned short* Ua = U128 + (((size_t)(bh * 8 + 2 * qb)) << 14);
  const unsigned short* Uc = U128 + (((size_t)(bh * 8 + 2 * qb + 1)) << 14);
  unsigned short* out = B256 + (((size_t)(bh * 4 + qb)) << 14);
  __shared__ unsigned short UaT[16384];
  __shared__ unsigned short T1T[16384];
#pragma unroll
  for (int i = 0; i < 8; ++i) {
    int cid = t + i * 256;
    int s = cid >> 4, ch = cid & 15;
    u16x8 v = *(const u16x8*)(Ua + s * 128 + ch * 8);
#pragma unroll
    for (int e = 0; e < 8; ++e) {
      int j = ch * 8 + e;
      int byt = ((j << 8) + (s << 1)) ^ ((j & 15) << 4);
      *(unsigned short*)((char*)UaT + byt) = v[e];
    }
  }
  __syncthreads();
  f32x4 a1[2][8];
#pragma unroll
  for (int m = 0; m < 2; ++m)
#pragma unroll
    for (int c = 0; c < 8; ++c) a1[m][c] = (f32x4){0.f, 0.f, 0.f, 0.f};
#pragma unroll
  for (int kc = 0; kc < 4; ++kc) {
    s16x8 af[2];
#pragma unroll
    for (int m = 0; m < 2; ++m)
      af[m] = *(const s16x8*)(Lb + base + ((size_t)(s0 + 128 + 32 * w + 16 * m + fr) << 10) + s0 + kc * 32 + fq * 8);
#pragma unroll
    for (int c = 0; c < 8; ++c) {
      int j = 16 * c + fr;
      s16x8 bb = *(const s16x8*)((char*)UaT + (((j << 8) + (kc << 6) + (fq << 4)) ^ ((j & 15) << 4)));
#pragma unroll
      for (int m = 0; m < 2; ++m)
        a1[m][c] = __builtin_amdgcn_mfma_f32_16x16x32_bf16(af[m], bb, a1[m][c], 0, 0, 0);
    }
  }
#pragma unroll
  for (int m = 0; m < 2; ++m) {
#pragma unroll
    for (int c = 0; c < 8; ++c) {
      int col = 16 * c + fr;
      int row0 = 32 * w + 16 * m + fq * 4;
      u16x4 pk;
#pragma unroll
      for (int r = 0; r < 4; ++r) pk[r] = f2bf(a1[m][c][r]);
      int byt = ((col << 8) + (row0 << 1)) ^ ((col & 15) << 4);
      *(u16x4*)((char*)T1T + byt) = pk;
    }
  }
  __syncthreads();
  f32x4 a2[2][8];
#pragma unroll
  for (int m = 0; m < 2; ++m)
#pragma unroll
    for (int c = 0; c < 8; ++c) a2[m][c] = (f32x4){0.f, 0.f, 0.f, 0.f};
#pragma unroll
  for (int kc = 0; kc < 4; ++kc) {
    s16x8 af[2];
#pragma unroll
    for (int m = 0; m < 2; ++m)
      af[m] = *(const s16x8*)(Uc + (32 * w + 16 * m + fr) * 128 + kc * 32 + fq * 8);
#pragma unroll
    for (int c = 0; c < 8; ++c) {
      int j = 16 * c + fr;
      s16x8 bb = *(const s16x8*)((char*)T1T + (((j << 8) + (kc << 6) + (fq << 4)) ^ ((j & 15) << 4)));
#pragma unroll
      for (int m = 0; m < 2; ++m)
        a2[m][c] = __builtin_amdgcn_mfma_f32_16x16x32_bf16(af[m], bb, a2[m][c], 0, 0, 0);
    }
  }
#pragma unroll
  for (int m = 0; m < 2; ++m) {
#pragma unroll
    for (int c = 0; c < 8; ++c) {
      int col = 16 * c + fr;
#pragma unroll
      for (int r = 0; r < 4; ++r)
        out[(32 * w + 16 * m + fq * 4 + r) * 128 + col] = f2bf(a2[m][c][r]);
    }
  }
}

// ================= solve256: 256-row band step; pipelined band GEMM + 3-piece apply =================
__global__ __launch_bounds__(256) void solve256(const unsigned short* __restrict__ WN,
    const unsigned short* __restrict__ Kk, const unsigned short* __restrict__ Lb,
    const unsigned short* __restrict__ U128, const unsigned short* __restrict__ B256,
    unsigned short* __restrict__ CT, int ib) {
  int jb = blockIdx.x, bh = blockIdx.y;
  int b = bh >> 4, h = bh & 15;
  int t = threadIdx.x, w = t >> 6, l = t & 63, fr = l & 15, fq = l >> 4;
  int s0 = ib * 256, j0 = jb * 128;
  size_t base = (size_t)bh << 20;
  __shared__ unsigned short sh[49152];      // 96KB: As[2] @0/16384, Bs[2] @32768/40960; rT aliases @0
  unsigned short* rT = sh;
  const unsigned short* Wb_ = WN + ((size_t)b << 20) + h * 64;
  const unsigned short* Kb_ = Kk + ((size_t)b << 20) + h * 64;

  f32x4 acc[4][8];
#pragma unroll
  for (int m = 0; m < 4; ++m)
#pragma unroll
    for (int c = 0; c < 8; ++c) acc[m][c] = (f32x4){0.f, 0.f, 0.f, 0.f};
  int nst = 1 + 4 * ib - 2 * jb; if (nst < 1) nst = 1;

#define STAGE_SV(buf, stp) {                                            \
  int rb = 2 * jb + (stp) - 1;                                          \
  _Pragma("unroll")                                                     \
  for (int i = 0; i < 8; ++i) {                                         \
    int cid = t + i * 256;                                              \
    int row = cid >> 3, ch = cid & 7;                                   \
    int chs = ch ^ (row & 7);                                           \
    const unsigned short* ga = ((stp) == 0)                             \
      ? Wb_ + ((size_t)(s0 + row) << 10) + chs * 8                      \
      : Lb + base + ((size_t)(s0 + row) << 10) + rb * 64 + chs * 8;     \
    glds16(ga, (char*)(sh + (buf) * 16384) + cid * 16);                 \
  }                                                                     \
  _Pragma("unroll")                                                     \
  for (int i = 0; i < 4; ++i) {                                         \
    int cid = t + i * 256;                                              \
    int row = cid >> 3, ch = cid & 7;                                   \
    int chs = ch ^ (row & 7);                                           \
    const unsigned short* gb = ((stp) == 0)                             \
      ? Kb_ + ((size_t)(j0 + row) << 10) + chs * 8                      \
      : CT + base + ((size_t)(j0 + row) << 10) + rb * 64 + chs * 8;     \
    glds16(gb, (char*)(sh + 32768 + (buf) * 8192) + cid * 16);          \
  } }

  STAGE_SV(0, 0);
  pipe_drain_barrier();
  int cur = 0;
  for (int st = 0; st < nst; ++st) {
    if (st + 1 < nst) STAGE_SV(cur ^ 1, st + 1);
    const char* Ab = (const char*)(sh + cur * 16384);
    const char* Bb = (const char*)(sh + 32768 + cur * 8192);
    __builtin_amdgcn_s_setprio(1);
#pragma unroll
    for (int kh = 0; kh < 2; ++kh) {
      s16x8 af[4], bfv[8];
#pragma unroll
      for (int m = 0; m < 4; ++m) {
        int ra = 64 * w + 16 * m + fr;
        af[m] = *(const s16x8*)(Ab + (((ra << 7) + (kh << 6) + (fq << 4)) ^ ((ra & 7) << 4)));
      }
#pragma unroll
      for (int c = 0; c < 8; ++c) {
        int rb2 = 16 * c + fr;
        bfv[c] = *(const s16x8*)(Bb + (((rb2 << 7) + (kh << 6) + (fq << 4)) ^ ((rb2 & 7) << 4)));
      }
#pragma unroll
      for (int m = 0; m < 4; ++m)
#pragma unroll
        for (int c = 0; c < 8; ++c)
          acc[m][c] = __builtin_amdgcn_mfma_f32_16x16x32_bf16(af[m], bfv[c], acc[m][c], 0, 0, 0);
    }
    __builtin_amdgcn_s_setprio(0);
    pipe_drain_barrier();
    cur ^= 1;
  }
#undef STAGE_SV
  // write rectT [j][s] (512B rows, XOR (j&15)<<4), mask j >= s
#pragma unroll
  for (int m = 0; m < 4; ++m) {
#pragma unroll
    for (int c = 0; c < 8; ++c) {
      int sl0 = 64 * w + 16 * m + fq * 4;
      int jl = 16 * c + fr;
      u16x4 pk;
#pragma unroll
      for (int r = 0; r < 4; ++r) {
        float v = acc[m][c][r];
        if (j0 + jl >= s0 + sl0 + r) v = 0.f;
        pk[r] = f2bf(v);
      }
      int byt = ((jl << 9) + (sl0 << 1)) ^ ((jl & 15) << 4);
      *(u16x4*)((char*)rT + byt) = pk;
    }
  }
  __syncthreads();
  const unsigned short* Ua = U128 + (((size_t)(bh * 8 + 2 * ib)) << 14);
  const unsigned short* Uc = U128 + (((size_t)(bh * 8 + 2 * ib + 1)) << 14);
  const unsigned short* Bm = B256 + (((size_t)(bh * 4 + ib)) << 14);
#pragma unroll
  for (int m = 0; m < 4; ++m)
#pragma unroll
    for (int c = 0; c < 8; ++c) acc[m][c] = (f32x4){0.f, 0.f, 0.f, 0.f};
  int nkc = (w < 2) ? 4 : 8;
  for (int kc = 0; kc < nkc; ++kc) {
    const unsigned short* src; int arow;
    if (w < 2) { src = Ua; arow = 64 * w; }
    else { src = (kc < 4) ? Bm : Uc; arow = 64 * (w - 2); }
    s16x8 uf[4];
#pragma unroll
    for (int m = 0; m < 4; ++m)
      uf[m] = *(const s16x8*)(src + (arow + 16 * m + fr) * 128 + (kc & 3) * 32 + fq * 8);
#pragma unroll
    for (int c = 0; c < 8; ++c) {
      int jl = 16 * c + fr;
      s16x8 bb = *(const s16x8*)((char*)rT + (((jl << 9) + (kc << 6) + (fq << 4)) ^ ((jl & 15) << 4)));
#pragma unroll
      for (int m = 0; m < 4; ++m)
        acc[m][c] = __builtin_amdgcn_mfma_f32_16x16x32_bf16(uf[m], bb, acc[m][c], 0, 0, 0);
    }
  }
#pragma unroll
  for (int m = 0; m < 4; ++m) {
#pragma unroll
    for (int c = 0; c < 8; ++c) {
      int jl = 16 * c + fr;
      int sb = 64 * w + 16 * m + fq * 4;
      u16x4 pk;
#pragma unroll
      for (int r = 0; r < 4; ++r) pk[r] = f2bf(acc[m][c][r]);
      *(u16x4*)(CT + base + ((size_t)(j0 + jl) << 10) + s0 + sb) = pk;
    }
  }
}

// ================= pv: online-softmax + P @ V; wave-independent (no barriers) =================
__global__ __launch_bounds__(256) void pv_kernel(const unsigned short* __restrict__ S,
    const unsigned short* __restrict__ VT, const float* __restrict__ Fc,
    unsigned short* __restrict__ Ob) {
  int idx = blockIdx.x;
  int bh = idx & 31, rank = idx >> 5;
  int tb = 15 - rank;
  int b = bh >> 4, h = bh & 15;
  int t0 = tb * 64;
  int t = threadIdx.x, w = t >> 6, l = t & 63, fr = l & 15, fq = l >> 4;
  int g = l >> 3, ch = l & 7;              // 8-lane row group / col chunk
  __shared__ unsigned short Pl[4][16 * 64];   // per-wave 2KB region
  size_t base = (size_t)bh << 20;
  float m0 = -1e30f, m1 = -1e30f, l0 = 0.f, l1 = 0.f;
  f32x4 acc[4];
#pragma unroll
  for (int c = 0; c < 4; ++c) acc[c] = (f32x4){0.f,0.f,0.f,0.f};
  for (int jb = 0; jb <= tb; ++jb) {
    int j0 = jb * 64;
    float sc[2];
#pragma unroll
    for (int i = 0; i < 2; ++i) {
      int row16 = g + i * 8;
      int row64 = 16 * w + row16;
      int grow = t0 + row64;
      u16x8 sv = *(const u16x8*)(S + base + ((size_t)grow << 10) + j0 + ch * 8);
      float4 f0 = *(const float4*)(Fc + bh * 1024 + j0 + ch * 8);
      float4 f1 = *(const float4*)(Fc + bh * 1024 + j0 + ch * 8 + 4);
      float vals[8];
      float tm = -1e30f;
#pragma unroll
      for (int e = 0; e < 8; ++e) {
        float fc = e < 4 ? ((const float*)&f0)[e] : ((const float*)&f1)[e - 4];
        float v = bf2f(sv[e]) * SM_SCALE - fc;
        if (jb == tb && ch * 8 + e > row64) v = -1e30f;
        vals[e] = v; tm = fmaxf(tm, v);
      }
      tm = fmaxf(tm, __shfl_xor(tm, 1));
      tm = fmaxf(tm, __shfl_xor(tm, 2));
      tm = fmaxf(tm, __shfl_xor(tm, 4));
      float mo = i ? m1 : m0;
      float mn = fmaxf(mo, tm);
      float s = __expf(mo - mn);
      u16x8 pv;
      float psum = 0.f;
#pragma unroll
      for (int e = 0; e < 8; ++e) {
        float p = __expf(vals[e] - mn);
        psum += p; pv[e] = f2bf(p);
      }
      int byt = ((row16 << 7) + (ch << 4)) ^ ((row16 & 7) << 4);
      *(u16x8*)((char*)Pl[w] + byt) = pv;
      psum += __shfl_xor(psum, 1);
      psum += __shfl_xor(psum, 2);
      psum += __shfl_xor(psum, 4);
      if (i) { m1 = mn; l1 = l1 * s + psum; } else { m0 = mn; l0 = l0 * s + psum; }
      sc[i] = s;
    }
    __builtin_amdgcn_wave_barrier();
    float cr[4];
#pragma unroll
    for (int r = 0; r < 4; ++r) {
      int rho = fq * 4 + r;
      int src = (rho & 7) * 8;
      float v0 = __shfl(sc[0], src);
      float v1 = __shfl(sc[1], src);
      cr[r] = (rho < 8) ? v0 : v1;
    }
#pragma unroll
    for (int c = 0; c < 4; ++c)
#pragma unroll
      for (int r = 0; r < 4; ++r) acc[c][r] *= cr[r];
#pragma unroll
    for (int kh = 0; kh < 2; ++kh) {
      s16x8 a = *(const s16x8*)((char*)Pl[w] + (((fr << 7) + (kh << 6) + (fq << 4)) ^ ((fr & 7) << 4)));
#pragma unroll
      for (int c = 0; c < 4; ++c) {
        s16x8 bb = *(const s16x8*)(VT + ((size_t)bh * 64 + 16 * c + fr) * 1024 + j0 + kh * 32 + fq * 8);
        acc[c] = __builtin_amdgcn_mfma_f32_16x16x32_bf16(a, bb, acc[c], 0, 0, 0);
      }
    }
    __builtin_amdgcn_wave_barrier();
  }
  float inv[4];
#pragma unroll
  for (int r = 0; r < 4; ++r) {
    int rho = fq * 4 + r;
    int src = (rho & 7) * 8;
    float v0 = __shfl(l0, src);
    float v1 = __shfl(l1, src);
    inv[r] = 1.f / ((rho < 8) ? v0 : v1);
  }
#pragma unroll
  for (int c = 0; c < 4; ++c) {
#pragma unroll
    for (int r = 0; r < 4; ++r) {
      int grow = t0 + 16 * w + fq * 4 + r;
      Ob[((size_t)(b * 1024) + grow) * 1024 + h * 64 + 16 * c + fr] = f2bf(acc[c][r] * inv[r]);
    }
  }
}

extern "C" void kernel_launch(void* const* d_in, const int* in_sizes, int n_in,
                              void* d_out, int out_size, void* d_ws, size_t ws_size,
                              hipStream_t stream) {
  const float* x    = (const float*)d_in[0];
  const float* Wq   = (const float*)d_in[1];
  const float* Wk   = (const float*)d_in[2];
  const float* Wv   = (const float*)d_in[3];
  const float* Wo   = (const float*)d_in[4];
  const float* Ww1  = (const float*)d_in[5];
  const float* Ww2  = (const float*)d_in[6];
  const float* Wb   = (const float*)d_in[7];
  const float* Wf   = (const float*)d_in[8];
  const float* delta= (const float*)d_in[9];

  char* ws = (char*)d_ws;
  unsigned short* xb   = (unsigned short*)(ws + OFF_XB);
  unsigned short* WqT  = (unsigned short*)(ws + OFF_WQT);
  unsigned short* WkT  = (unsigned short*)(ws + OFF_WKT);
  unsigned short* WvT  = (unsigned short*)(ws + OFF_WVT);
  unsigned short* WoT  = (unsigned short*)(ws + OFF_WOT);
  unsigned short* W1c  = (unsigned short*)(ws + OFF_W1C);
  unsigned short* W2T  = (unsigned short*)(ws + OFF_W2T);
  float*          Beta = (float*)(ws + OFF_BETA);
  unsigned short* Q16  = (unsigned short*)(ws + OFF_Q16);
  unsigned short* K16  = (unsigned short*)(ws + OFF_K16);
  unsigned short* VT   = (unsigned short*)(ws + OFF_VT);
  unsigned short* WN16 = (unsigned short*)(ws + OFF_WN16);
  unsigned short* WB16 = (unsigned short*)(ws + OFF_WB16);
  unsigned short* WNF16= (unsigned short*)(ws + OFF_WNF);
  unsigned short* ObB  = (unsigned short*)(ws + OFF_OB);
  unsigned short* BFT  = (unsigned short*)(ws + OFF_BFT);
  float*          Fc   = (float*)(ws + OFF_FC);
  unsigned short* Lbuf = (unsigned short*)(ws + OFF_L);
  unsigned short* Sbuf = (unsigned short*)(ws + OFF_L);
  unsigned short* CT   = (unsigned short*)(ws + OFF_CT);
  unsigned short* Gbuf = (unsigned short*)(ws + OFF_G);
  float*          BL   = (float*)(ws + OFF_BL);
  unsigned short* U128 = (unsigned short*)(ws + OFF_U128);
  unsigned short* B256 = (unsigned short*)(ws + OFF_B256);

  dim3 blk(256);
  // prep (all transposes + casts + BFT 128-row)
  prep_all<<<2160, blk, 0, stream>>>(Wq, Wk, Wv, Wo, Ww1, Ww2, x, Wb, Wf,
                                     WqT, WkT, WvT, WoT, W1c, W2T, xb, BFT);
  // WfusedT (256 tiles) + BL (32 tiles) in one 288-block launch
  wfuse_bl<<<288, blk, 0, stream>>>(W2T, W1c, xb, BFT, WN16, BL);
  // Q, K, VT, WNF in one 512-block launch (XCD-grouped, pipelined, no tail)
  proj_big<<<512, blk, 0, stream>>>(xb, WqT, WkT, WvT, WN16, Q16, K16, VT, WNF16);
  // beta/logsigmoid/cumsum fused
  bgfc<<<32, blk, 0, stream>>>(BL, delta, Beta, Fc);
  wnorm2<<<2048, blk, 0, stream>>>(WNF16, Beta, WN16, WB16);
  // L and G (both stored NEGATED)
  pairLG<<<dim3(36 * 32), blk, 0, stream>>>(WN16, Q16, WB16, Lbuf, Gbuf);
  // triangular solve: fused inverses -> 256 off-diag piece -> 4 band steps
  invbuild<<<dim3(8,32), blk, 0, stream>>>(Lbuf, U128);
  u256build<<<dim3(4,32), blk, 0, stream>>>(Lbuf, U128, B256);
  for (int ib = 0; ib < 4; ++ib)
    solve256<<<dim3(2 * ib + 2, 32), blk, 0, stream>>>(WN16, K16, Lbuf, U128, B256, CT, ib);
  // S = QK^T + Gneg C (sorted band grid; reuses L region; pipelined)
  score128s<<<dim3(36 * 32), blk, 0, stream>>>(Q16, K16, Gbuf, CT, Sbuf);
  // online softmax + PV (wave-independent)
  pv_kernel<<<dim3(512), blk, 0, stream>>>(Sbuf, VT, Fc, ObB);
  // output projection (f32 out; XCD-grouped, pipelined)
  gemm_outproj<<<512, blk, 0, stream>>>(ObB, WoT, (float*)d_out);
}

// Round 16
// 280.872 us; speedup vs baseline: 1.0940x; 1.0032x over previous
//
#include <hip/hip_runtime.h>
#include <hip/hip_bf16.h>

#define DEV static __device__ __forceinline__

constexpr float SM_SCALE = 0.125f;   // hd^-0.5, hd=64

typedef __attribute__((ext_vector_type(8))) short s16x8;
typedef __attribute__((ext_vector_type(8))) unsigned short u16x8;
typedef __attribute__((ext_vector_type(4))) unsigned short u16x4;
typedef __attribute__((ext_vector_type(4))) float f32x4;

DEV float bf2f(unsigned short u) {
  union { unsigned int i; float f; } v; v.i = ((unsigned int)u) << 16; return v.f;
}
DEV unsigned short f2bf(float f) {
  union { float f; unsigned int i; } v; v.f = f;
  unsigned int r = v.i + 0x7fffu + ((v.i >> 16) & 1u);
  return (unsigned short)(r >> 16);
}
DEV void tri_unrank(int r, int& k, int& i) {
  k = (int)((sqrtf(8.f * r + 1.f) - 1.f) * 0.5f);
  while (k * (k + 1) / 2 > r) --k;
  while ((k + 1) * (k + 2) / 2 <= r) ++k;
  i = r - k * (k + 1) / 2;
}
// async global->LDS, 16B per lane; dest must be wave-linear (base + lane*16)
DEV void glds16(const void* g, void* l) {
  __builtin_amdgcn_global_load_lds(
      (const __attribute__((address_space(1))) void*)g,
      (__attribute__((address_space(3))) void*)l, 16, 0, 0);
}
DEV void pipe_drain_barrier() {
  asm volatile("s_waitcnt vmcnt(0)" ::: "memory");
  __builtin_amdgcn_s_barrier();
}

// ---------- workspace layout (bytes) ----------
constexpr size_t OFF_XB   = 0;                       // 4MB xb bf16 [2048][1024]
constexpr size_t OFF_WQT  = 4194304;                 // 2MB
constexpr size_t OFF_WKT  = 6291456;                 // 2MB
constexpr size_t OFF_WVT  = 8388608;
constexpr size_t OFF_WOT  = 10485760;
constexpr size_t OFF_W1C  = 12582912;                // 128KB bf16 Ww1 cast (1024x64)
constexpr size_t OFF_W2T  = 12713984;                // 128KB
constexpr size_t OFF_BETA = 12582912;                // reuse W1C after wfuse
constexpr size_t OFF_Q16  = 12845056;                // 4MB bf16 2048x1024
constexpr size_t OFF_K16  = 17039360;                // 4MB
constexpr size_t OFF_VT   = 21233664;                // 4MB  VT[b][64h*d][1024n]
constexpr size_t OFF_WN16 = 25427968;                // 4MB; holds WfusedT until wnorm2
constexpr size_t OFF_WB16 = 29622272;                // 4MB
constexpr size_t OFF_WNF  = 33816576;                // 4MB (reused as Ob)
constexpr size_t OFF_OB   = 33816576;
constexpr size_t OFF_BFT  = 38010880;                // 256KB bf16 (128x1024)
constexpr size_t OFF_FC   = 38273024;                // 128KB
constexpr size_t OFF_L    = 38404096;                // 64MB, stores -L (reused as S)
constexpr size_t OFF_CT   = 105512960;               // 64MB
constexpr size_t OFF_G    = 172621824;               // 64MB, stores -G
constexpr size_t OFF_BL   = 239730688;               // 512KB f32 2048x64
constexpr size_t OFF_U128 = 244187136;               // 8MB bf16 [32][8][128][128]
constexpr size_t OFF_B256 = 252575744;               // 4MB bf16 [32][4][128][128]

// ================= fused prep: transposes + casts + BFT(128 rows); grid 2160 =================
__global__ __launch_bounds__(256) void prep_all(
    const float* __restrict__ W0, const float* __restrict__ W1,
    const float* __restrict__ W2, const float* __restrict__ W3,
    const float* __restrict__ Ww1, const float* __restrict__ Ww2,
    const float* __restrict__ x, const float* __restrict__ Wb,
    const float* __restrict__ Wf,
    unsigned short* __restrict__ D0, unsigned short* __restrict__ D1,
    unsigned short* __restrict__ D2, unsigned short* __restrict__ D3,
    unsigned short* __restrict__ W1c, unsigned short* __restrict__ W2T,
    unsigned short* __restrict__ xb, unsigned short* __restrict__ BFT) {
  int bidx = blockIdx.x;
  int t = threadIdx.x;
  if (bidx >= 2096) {                      // BFT build (64 blocks, 128x1024)
    int e0 = ((bidx - 2096) * 256 + t) * 8;
    int j = e0 >> 10, i0 = e0 & 1023;
    u16x8 o;
#pragma unroll
    for (int e = 0; e < 8; ++e) {
      int i = i0 + e;
      float v = 0.f;
      if (j < 16) v = Wb[i * 16 + j];
      else if (j < 32) v = Wf[i * 16 + (j - 16)];
      o[e] = f2bf(v);
    }
    *(u16x8*)(BFT + e0) = o;
    return;
  }
  if (bidx >= 2064) {                      // W1 cast (32 blocks)
    int i = ((bidx - 2064) * 256 + t) * 8;
    float4 a = *(const float4*)(Ww1 + i);
    float4 b = *(const float4*)(Ww1 + i + 4);
    u16x8 o;
    o[0] = f2bf(a.x); o[1] = f2bf(a.y); o[2] = f2bf(a.z); o[3] = f2bf(a.w);
    o[4] = f2bf(b.x); o[5] = f2bf(b.y); o[6] = f2bf(b.z); o[7] = f2bf(b.w);
    *(u16x8*)(W1c + i) = o;
    return;
  }
  if (bidx >= 1040) {                      // x cast (1024 blocks)
    int i = ((bidx - 1040) * 256 + t) * 8;
    float4 a = *(const float4*)(x + i);
    float4 b = *(const float4*)(x + i + 4);
    u16x8 o;
    o[0] = f2bf(a.x); o[1] = f2bf(a.y); o[2] = f2bf(a.z); o[3] = f2bf(a.w);
    o[4] = f2bf(b.x); o[5] = f2bf(b.y); o[6] = f2bf(b.z); o[7] = f2bf(b.w);
    *(u16x8*)(xb + i) = o;
    return;
  }
  const float* src; unsigned short* dst; int R, C, c0, r0;
  if (bidx >= 1024) {                      // W2T transpose (16 blocks)
    src = Ww2; dst = W2T; R = 64; C = 1024;
    c0 = (bidx - 1024) * 64; r0 = 0;
  } else {
    int z = bidx >> 8, xy = bidx & 255;
    src = z == 0 ? W0 : z == 1 ? W1 : z == 2 ? W2 : W3;
    dst = z == 0 ? D0 : z == 1 ? D1 : z == 2 ? D2 : D3;
    R = 1024; C = 1024;
    c0 = (xy & 15) * 64; r0 = (xy >> 4) * 64;
  }
  __shared__ float tile[64 * 65];
  // vectorized load: float4 per lane (64 rows x 16 float4-cols = 1024 chunks)
#pragma unroll
  for (int i = 0; i < 4; ++i) {
    int lin = t + i * 256; int r = lin >> 4, c4 = lin & 15;
    float4 v = *(const float4*)(src + (size_t)(r0 + r) * C + c0 + c4 * 4);
    tile[r * 65 + c4 * 4 + 0] = v.x;
    tile[r * 65 + c4 * 4 + 1] = v.y;
    tile[r * 65 + c4 * 4 + 2] = v.z;
    tile[r * 65 + c4 * 4 + 3] = v.w;
  }
  __syncthreads();
  // vectorized store: u16x4 per lane (64 cols x 16 row-quads)
#pragma unroll
  for (int i = 0; i < 4; ++i) {
    int lin = t + i * 256; int c = lin >> 4, r4 = lin & 15;
    u16x4 o;
#pragma unroll
    for (int e = 0; e < 4; ++e) o[e] = f2bf(tile[(r4 * 4 + e) * 65 + c]);
    *(u16x4*)(dst + (size_t)(c0 + c) * R + r0 + r4 * 4) = o;
  }
}

// beta + log_sigmoid + cumsum fused; grid 32 (bh)
__global__ __launch_bounds__(256) void bgfc(const float* __restrict__ BL,
    const float* __restrict__ delta, float* __restrict__ Beta, float* __restrict__ Fc) {
  int bh = blockIdx.x;
  int b = bh >> 4, h = bh & 15;
  int t = threadIdx.x;
  __shared__ float buf[1024];
  __shared__ float tsum[256];
  float dh = delta[h];
#pragma unroll
  for (int i = 0; i < 4; ++i) {
    int n = t + i * 256;
    int row = (b << 10) + n;
    float braw = BL[row * 64 + h];
    Beta[row * 16 + h] = 2.f / (1.f + __expf(-braw));
    float lraw = BL[row * 64 + 16 + h] + dh;
    buf[n] = (lraw >= 0.f) ? -log1pf(__expf(-lraw)) : (lraw - log1pf(__expf(lraw)));
  }
  __syncthreads();
  float loc[4]; float run = 0.f;
#pragma unroll
  for (int i = 0; i < 4; ++i) { run += buf[t * 4 + i]; loc[i] = run; }
  tsum[t] = run;
  __syncthreads();
  for (int off = 1; off < 256; off <<= 1) {
    float add = (t >= off) ? tsum[t - off] : 0.f;
    __syncthreads();
    tsum[t] += add;
    __syncthreads();
  }
  float excl = tsum[t] - run;
#pragma unroll
  for (int i = 0; i < 4; ++i) Fc[bh * 1024 + t * 4 + i] = excl + loc[i];
}

// ================= wfuse + BL: 288 blocks (256 WfusedT tiles + 32 BL tiles) =================
__global__ __launch_bounds__(256) void wfuse_bl(
    const unsigned short* __restrict__ W2T, const unsigned short* __restrict__ W1c,
    const unsigned short* __restrict__ xb, const unsigned short* __restrict__ BFT,
    unsigned short* __restrict__ WF, float* __restrict__ BL) {
  int v = blockIdx.x;
  const unsigned short *A, *BT; int m0, n0, K, mode;
  if (v < 256) { A = W2T; BT = W1c; m0 = (v >> 4) * 64; n0 = (v & 15) * 64; K = 64; mode = 0; }
  else { A = xb; BT = BFT; m0 = (v - 256) * 64; n0 = 0; K = 1024; mode = 1; }
  __shared__ unsigned short As[2 * 4096];
  __shared__ unsigned short Bs[2 * 4096];
  int t = threadIdx.x;
  int w = t >> 6, l = t & 63, fr = l & 15;
  int koB = (l >> 4) * 16;
  f32x4 acc[4];
#pragma unroll
  for (int c = 0; c < 4; ++c) acc[c] = (f32x4){0.f, 0.f, 0.f, 0.f};

#define STAGE_W(buf, k0) {                                              \
  _Pragma("unroll")                                                     \
  for (int i = 0; i < 2; ++i) {                                         \
    int cid = t + i * 256;                                              \
    int row = cid >> 3, ch = cid & 7;                                   \
    int chs = ch ^ (row & 7);                                           \
    glds16(A + (size_t)(m0 + row) * K + (k0) + chs * 8, (char*)(As + (buf) * 4096) + cid * 16); \
    glds16(BT + (size_t)(n0 + row) * K + (k0) + chs * 8, (char*)(Bs + (buf) * 4096) + cid * 16); \
  } }

  int nt = K >> 6;
  STAGE_W(0, 0);
  pipe_drain_barrier();
  int cur = 0;
  for (int kt = 0; kt < nt; ++kt) {
    if (kt + 1 < nt) STAGE_W(cur ^ 1, (kt + 1) * 64);
    const char* Ab = (const char*)(As + cur * 4096);
    const char* Bb = (const char*)(Bs + cur * 4096);
    __builtin_amdgcn_s_setprio(1);
#pragma unroll
    for (int kh = 0; kh < 2; ++kh) {
      int ra = 16 * w + fr;
      s16x8 a = *(const s16x8*)(Ab + (((ra << 7) + (kh << 6) + koB) ^ ((ra & 7) << 4)));
#pragma unroll
      for (int c = 0; c < 4; ++c) {
        int rb = 16 * c + fr;
        s16x8 bb = *(const s16x8*)(Bb + (((rb << 7) + (kh << 6) + koB) ^ ((rb & 7) << 4)));
        acc[c] = __builtin_amdgcn_mfma_f32_16x16x32_bf16(a, bb, acc[c], 0, 0, 0);
      }
    }
    __builtin_amdgcn_s_setprio(0);
    pipe_drain_barrier();
    cur ^= 1;
  }
#undef STAGE_W
  int rbase = m0 + 16 * w + ((l >> 4) << 2);
#pragma unroll
  for (int c = 0; c < 4; ++c) {
    int col = n0 + 16 * c + fr;
#pragma unroll
    for (int r = 0; r < 4; ++r) {
      if (mode == 0) WF[(size_t)(rbase + r) * 1024 + col] = f2bf(acc[c][r]);
      else BL[(size_t)(rbase + r) * 64 + col] = acc[c][r];
    }
  }
}

// ================= mega projection: Q,K + VT + WNF; XCD-grouped 512 blocks =================
__global__ __launch_bounds__(256) void proj_big(const unsigned short* __restrict__ xb,
    const unsigned short* __restrict__ WqT, const unsigned short* __restrict__ WkT,
    const unsigned short* __restrict__ WvT, const unsigned short* __restrict__ WfT,
    unsigned short* __restrict__ Q16, unsigned short* __restrict__ K16,
    unsigned short* __restrict__ VT, unsigned short* __restrict__ WNF) {
  int sg = blockIdx.x;                       // 512 = 8 * 64 exactly
  int virt = (sg % 8) * 64 + (sg / 8);       // bijective chunked XCD swizzle
  const unsigned short *A, *BT; unsigned short* out; int m0, n0;
  if (virt < 256) {                          // Q/K: 16my x 16nx in 4x4 groups, 2x2 supergroups
    int g = virt >> 4, in = virt & 15;
    int ssb = g >> 2, gin = g & 3;
    int mb = (ssb >> 1) * 2 + (gin >> 1);
    int nb = (ssb & 1) * 2 + (gin & 1);
    int my = mb * 4 + (in >> 2);
    int nx = nb * 4 + (in & 3);
    m0 = my * 128; A = xb;
    if (nx < 8) { BT = WqT; out = Q16; n0 = nx * 128; }
    else { BT = WkT; out = K16; n0 = (nx - 8) * 128; }
  } else if (virt < 384) {                   // VT: per batch 8x8 in 4x4 groups
    int r = virt - 256; int bz = r >> 6; int rr = r & 63;
    int g = rr >> 4, in = rr & 15;
    int my = (g >> 1) * 4 + (in >> 2);
    int nx = (g & 1) * 4 + (in & 3);
    m0 = my * 128; n0 = nx * 128;
    A = WvT; BT = xb + ((size_t)bz << 20); out = VT + ((size_t)bz << 20);
  } else {                                   // WNF: 16my x 8nx in 4x4 groups
    int r = virt - 384;
    int g = r >> 4, in = r & 15;
    int my = (g >> 1) * 4 + (in >> 2);
    int nx = (g & 1) * 4 + (in & 3);
    m0 = my * 128; n0 = nx * 128;
    A = xb; BT = WfT; out = WNF;
  }
  int t = threadIdx.x;
  int w = t >> 6, l = t & 63;
  int wr = w >> 1, wc = w & 1;
  int fr = l & 15, fq = l >> 4;
  __shared__ unsigned short As[2 * 8192];
  __shared__ unsigned short Bs[2 * 8192];
  f32x4 acc[4][4];
#pragma unroll
  for (int m = 0; m < 4; ++m)
#pragma unroll
    for (int c = 0; c < 4; ++c) acc[m][c] = (f32x4){0.f, 0.f, 0.f, 0.f};

#define STAGE_PB(buf, k0) {                                             \
  _Pragma("unroll")                                                     \
  for (int i = 0; i < 4; ++i) {                                         \
    int cid = t + i * 256;                                              \
    int row = cid >> 3, ch = cid & 7;                                   \
    int chs = ch ^ (row & 7);                                           \
    glds16(A + (size_t)(m0 + row) * 1024 + (k0) + chs * 8, (char*)(As + (buf) * 8192) + cid * 16); \
    glds16(BT + (size_t)(n0 + row) * 1024 + (k0) + chs * 8, (char*)(Bs + (buf) * 8192) + cid * 16); \
  } }

  STAGE_PB(0, 0);
  pipe_drain_barrier();
  int cur = 0;
  for (int kt = 0; kt < 16; ++kt) {
    if (kt < 15) STAGE_PB(cur ^ 1, (kt + 1) * 64);
    const char* Ab = (const char*)(As + cur * 8192);
    const char* Bb = (const char*)(Bs + cur * 8192);
    __builtin_amdgcn_s_setprio(1);
#pragma unroll
    for (int kh = 0; kh < 2; ++kh) {
      s16x8 af[4], bfv[4];
#pragma unroll
      for (int m = 0; m < 4; ++m) {
        int ra = wr * 64 + 16 * m + fr;
        af[m] = *(const s16x8*)(Ab + (((ra << 7) + (kh << 6) + (fq << 4)) ^ ((ra & 7) << 4)));
      }
#pragma unroll
      for (int c = 0; c < 4; ++c) {
        int rb = wc * 64 + 16 * c + fr;
        bfv[c] = *(const s16x8*)(Bb + (((rb << 7) + (kh << 6) + (fq << 4)) ^ ((rb & 7) << 4)));
      }
#pragma unroll
      for (int m = 0; m < 4; ++m)
#pragma unroll
        for (int c = 0; c < 4; ++c)
          acc[m][c] = __builtin_amdgcn_mfma_f32_16x16x32_bf16(af[m], bfv[c], acc[m][c], 0, 0, 0);
    }
    __builtin_amdgcn_s_setprio(0);
    pipe_drain_barrier();
    cur ^= 1;
  }
#undef STAGE_PB
#pragma unroll
  for (int m = 0; m < 4; ++m) {
#pragma unroll
    for (int c = 0; c < 4; ++c) {
      int col = n0 + wc * 64 + 16 * c + fr;
#pragma unroll
      for (int r = 0; r < 4; ++r) {
        int grow = m0 + wr * 64 + 16 * m + fq * 4 + r;
        out[(size_t)grow * 1024 + col] = f2bf(acc[m][c][r]);
      }
    }
  }
}

// ================= output projection: 128x64 tiles, 256 blocks (1 round), f32 out =================
__global__ __launch_bounds__(256) void gemm_outproj(const unsigned short* __restrict__ A,
    const unsigned short* __restrict__ BT, float* __restrict__ out) {
  int sg = blockIdx.x;                       // 256 = 8 * 32 exactly
  int virt = (sg & 7) * 32 + (sg >> 3);      // bijective chunked XCD swizzle
  int my = virt >> 4, nx = virt & 15;        // 16 x 16
  int m0 = my * 128, n0 = nx * 64;
  const int K = 1024, N = 1024;
  __shared__ unsigned short sh[24576];       // 48KB: A[2] @0/8192, B[2] @16384/20480
  int t = threadIdx.x;
  int w = t >> 6, l = t & 63, fr = l & 15, fq = l >> 4;
  f32x4 acc[2][4];
#pragma unroll
  for (int m = 0; m < 2; ++m)
#pragma unroll
    for (int c = 0; c < 4; ++c) acc[m][c] = (f32x4){0.f, 0.f, 0.f, 0.f};

#define STAGE_O(buf, k0) {                                              \
  _Pragma("unroll")                                                     \
  for (int i = 0; i < 4; ++i) {                                         \
    int cid = t + i * 256;                                              \
    int row = cid >> 3, ch = cid & 7;                                   \
    int chs = ch ^ (row & 7);                                           \
    glds16(A + (size_t)(m0 + row) * K + (k0) + chs * 8,                 \
           (char*)(sh + (buf) * 8192) + cid * 16);                      \
  }                                                                     \
  _Pragma("unroll")                                                     \
  for (int i = 0; i < 2; ++i) {                                         \
    int cid = t + i * 256;                                              \
    int row = cid >> 3, ch = cid & 7;                                   \
    int chs = ch ^ (row & 7);                                           \
    glds16(BT + (size_t)(n0 + row) * K + (k0) + chs * 8,                \
           (char*)(sh + 16384 + (buf) * 4096) + cid * 16);              \
  } }

  STAGE_O(0, 0);
  pipe_drain_barrier();
  int cur = 0;
  for (int kt = 0; kt < 16; ++kt) {
    if (kt + 1 < 16) STAGE_O(cur ^ 1, (kt + 1) * 64);
    const char* Ab = (const char*)(sh + cur * 8192);
    const char* Bb = (const char*)(sh + 16384 + cur * 4096);
    __builtin_amdgcn_s_setprio(1);
#pragma unroll
    for (int kh = 0; kh < 2; ++kh) {
      s16x8 af[2], bfv[4];
#pragma unroll
      for (int m = 0; m < 2; ++m) {
        int ra = 32 * w + 16 * m + fr;
        af[m] = *(const s16x8*)(Ab + (((ra << 7) + (kh << 6) + (fq << 4)) ^ ((ra & 7) << 4)));
      }
#pragma unroll
      for (int c = 0; c < 4; ++c) {
        int rb = 16 * c + fr;
        bfv[c] = *(const s16x8*)(Bb + (((rb << 7) + (kh << 6) + (fq << 4)) ^ ((rb & 7) << 4)));
      }
#pragma unroll
      for (int m = 0; m < 2; ++m)
#pragma unroll
        for (int c = 0; c < 4; ++c)
          acc[m][c] = __builtin_amdgcn_mfma_f32_16x16x32_bf16(af[m], bfv[c], acc[m][c], 0, 0, 0);
    }
    __builtin_amdgcn_s_setprio(0);
    pipe_drain_barrier();
    cur ^= 1;
  }
#undef STAGE_O
#pragma unroll
  for (int m = 0; m < 2; ++m) {
#pragma unroll
    for (int c = 0; c < 4; ++c) {
      int col = n0 + 16 * c + fr;
#pragma unroll
      for (int r = 0; r < 4; ++r) {
        int grow = m0 + 32 * w + 16 * m + fq * 4 + r;
        out[(size_t)grow * N + col] = acc[m][c][r];
      }
    }
  }
}

// ================= w normalize + beta-scale =================
__global__ __launch_bounds__(256) void wnorm2(const unsigned short* __restrict__ WNF,
    const float* __restrict__ Beta, unsigned short* __restrict__ WN,
    unsigned short* __restrict__ WB) {
  int row = blockIdx.x;
  int wave = threadIdx.x >> 6, lane = threadIdx.x & 63;
#pragma unroll
  for (int i = 0; i < 4; ++i) {
    int hh = wave * 4 + i;
    size_t idx = ((size_t)row << 10) + hh * 64 + lane;
    float v = bf2f(WNF[idx]);
    float ss = v * v;
#pragma unroll
    for (int off = 1; off < 64; off <<= 1) ss += __shfl_xor(ss, off);
    float wn = v * rsqrtf(ss + 1e-6f);
    WN[idx] = f2bf(wn);
    WB[idx] = f2bf(wn * Beta[row * 16 + hh]);
  }
}

// ================= pair fused: writes NEGATED L and G =================
__global__ __launch_bounds__(256) void pairLG(const unsigned short* __restrict__ WN,
    const unsigned short* __restrict__ Q, const unsigned short* __restrict__ WB,
    unsigned short* __restrict__ Lg, unsigned short* __restrict__ Gg) {
  int idx = blockIdx.x;
  int bh = idx & 31, r0r = idx >> 5;
  int tb2, jb2; tri_unrank(r0r, tb2, jb2);
  int b = bh >> 4, h = bh & 15;
  int m0 = tb2 * 128, n0 = jb2 * 128;
  int t = threadIdx.x;
  int w = t >> 6, l = t & 63;
  int wr = w >> 1, wc = w & 1;
  int fr = l & 15, fq = l >> 4;
  __shared__ unsigned short As[128 * 64];
  __shared__ unsigned short Bs[128 * 64];
  const unsigned short* WNb = WN + ((size_t)b << 20) + h * 64;
  const unsigned short* Qb  = Q + ((size_t)b << 20) + h * 64;
  const unsigned short* WBb = WB + ((size_t)b << 20) + h * 64;
  size_t base = (size_t)bh << 20;
#pragma unroll
  for (int i = 0; i < 4; ++i) {
    int cid = t + i * 256;
    int row = cid >> 3, ch = cid & 7;
    int chs = ch ^ (row & 7);
    glds16(WNb + ((size_t)(m0 + row) << 10) + chs * 8, (char*)As + cid * 16);
    glds16(WBb + ((size_t)(n0 + row) << 10) + chs * 8, (char*)Bs + cid * 16);
  }
  __syncthreads();
  for (int pass = 0; pass < 2; ++pass) {
    f32x4 acc[4][4];
#pragma unroll
    for (int m = 0; m < 4; ++m)
#pragma unroll
      for (int c = 0; c < 4; ++c) acc[m][c] = (f32x4){0.f, 0.f, 0.f, 0.f};
#pragma unroll
    for (int kh = 0; kh < 2; ++kh) {
      s16x8 af[4], bfv[4];
#pragma unroll
      for (int m = 0; m < 4; ++m) {
        int ra = wr * 64 + 16 * m + fr;
        af[m] = *(const s16x8*)((char*)As + (((ra << 7) + (kh << 6) + (fq << 4)) ^ ((ra & 7) << 4)));
      }
#pragma unroll
      for (int c = 0; c < 4; ++c) {
        int rb = wc * 64 + 16 * c + fr;
        bfv[c] = *(const s16x8*)((char*)Bs + (((rb << 7) + (kh << 6) + (fq << 4)) ^ ((rb & 7) << 4)));
      }
#pragma unroll
      for (int m = 0; m < 4; ++m)
#pragma unroll
        for (int c = 0; c < 4; ++c)
          acc[m][c] = __builtin_amdgcn_mfma_f32_16x16x32_bf16(af[m], bfv[c], acc[m][c], 0, 0, 0);
    }
    unsigned short* dst = pass ? Gg : Lg;
#pragma unroll
    for (int m = 0; m < 4; ++m) {
#pragma unroll
      for (int c = 0; c < 4; ++c) {
        int gj = n0 + wc * 64 + 16 * c + fr;
#pragma unroll
        for (int r = 0; r < 4; ++r) {
          int gi = m0 + wr * 64 + 16 * m + fq * 4 + r;
          bool keep = pass ? (gj <= gi) : (gj < gi);
          dst[base + ((size_t)gi << 10) + gj] = f2bf(keep ? -acc[m][c][r] : 0.f);
        }
      }
    }
    if (pass == 0) {
      __syncthreads();
#pragma unroll
      for (int i = 0; i < 4; ++i) {
        int cid = t + i * 256;
        int row = cid >> 3, ch = cid & 7;
        int chs = ch ^ (row & 7);
        glds16(Qb + ((size_t)(m0 + row) << 10) + chs * 8, (char*)As + cid * 16);
      }
      __syncthreads();
    }
  }
}

// ================= score: S = Q K^T + Gneg @ C, sorted 1D grid; 2-phase pipeline =================
__global__ __launch_bounds__(256) void score128s(const unsigned short* __restrict__ Q,
    const unsigned short* __restrict__ Kk, const unsigned short* __restrict__ G,
    const unsigned short* __restrict__ CT, unsigned short* __restrict__ Sg) {
  int idx = blockIdx.x;
  int bh = idx & 31, r0r = idx >> 5;
  int k, i; tri_unrank(r0r, k, i);
  int tb2 = (7 - k) + i, jb2 = i;
  int b = bh >> 4, h = bh & 15;
  int m0 = tb2 * 128, n0 = jb2 * 128;
  int t = threadIdx.x;
  int w = t >> 6, l = t & 63;
  int wr = w >> 1, wc = w & 1;
  int fr = l & 15, fq = l >> 4;
  __shared__ unsigned short As[2 * 8192];
  __shared__ unsigned short Bs[2 * 8192];
  size_t base = (size_t)bh << 20;
  const unsigned short* Qb_ = Q + ((size_t)b << 20) + h * 64;
  const unsigned short* Kb_ = Kk + ((size_t)b << 20) + h * 64;
  const unsigned short* Gb_ = G + base;
  const unsigned short* Cb_ = CT + base;
  int kbase = jb2 * 128;
  int nsteps = 1 + (tb2 - jb2 + 1) * 2;
  f32x4 acc[4][4];
#pragma unroll
  for (int m = 0; m < 4; ++m)
#pragma unroll
    for (int c = 0; c < 4; ++c) acc[m][c] = (f32x4){0.f, 0.f, 0.f, 0.f};

#define STAGE_SC(buf, stp) {                                            \
  const unsigned short* pa; const unsigned short* pb; int koff;         \
  if ((stp) == 0) { pa = Qb_; pb = Kb_; koff = 0; }                     \
  else { pa = Gb_; pb = Cb_; koff = kbase + ((stp) - 1) * 64; }         \
  _Pragma("unroll")                                                     \
  for (int i2 = 0; i2 < 4; ++i2) {                                      \
    int cid = t + i2 * 256;                                             \
    int row = cid >> 3, ch = cid & 7;                                   \
    int chs = ch ^ (row & 7);                                           \
    glds16(pa + ((size_t)(m0 + row) << 10) + koff + chs * 8, (char*)(As + (buf) * 8192) + cid * 16); \
    glds16(pb + ((size_t)(n0 + row) << 10) + koff + chs * 8, (char*)(Bs + (buf) * 8192) + cid * 16); \
  } }

  STAGE_SC(0, 0);
  pipe_drain_barrier();
  int cur = 0;
  for (int step = 0; step < nsteps; ++step) {
    if (step + 1 < nsteps) STAGE_SC(cur ^ 1, step + 1);
    const char* Ab = (const char*)(As + cur * 8192);
    const char* Bb = (const char*)(Bs + cur * 8192);
    __builtin_amdgcn_s_setprio(1);
#pragma unroll
    for (int kh = 0; kh < 2; ++kh) {
      s16x8 af[4], bfv[4];
#pragma unroll
      for (int m = 0; m < 4; ++m) {
        int ra = wr * 64 + 16 * m + fr;
        af[m] = *(const s16x8*)(Ab + (((ra << 7) + (kh << 6) + (fq << 4)) ^ ((ra & 7) << 4)));
      }
#pragma unroll
      for (int c = 0; c < 4; ++c) {
        int rb = wc * 64 + 16 * c + fr;
        bfv[c] = *(const s16x8*)(Bb + (((rb << 7) + (kh << 6) + (fq << 4)) ^ ((rb & 7) << 4)));
      }
#pragma unroll
      for (int m = 0; m < 4; ++m)
#pragma unroll
        for (int c = 0; c < 4; ++c)
          acc[m][c] = __builtin_amdgcn_mfma_f32_16x16x32_bf16(af[m], bfv[c], acc[m][c], 0, 0, 0);
    }
    __builtin_amdgcn_s_setprio(0);
    pipe_drain_barrier();
    cur ^= 1;
  }
#undef STAGE_SC
#pragma unroll
  for (int m = 0; m < 4; ++m) {
#pragma unroll
    for (int c = 0; c < 4; ++c) {
      int gj = n0 + wc * 64 + 16 * c + fr;
#pragma unroll
      for (int r = 0; r < 4; ++r) {
        int gi = m0 + wr * 64 + 16 * m + fq * 4 + r;
        Sg[base + ((size_t)gi << 10) + gj] = f2bf(acc[m][c][r]);
      }
    }
  }
}

// ================= invbuild: 2x inv64 + U128 assembly in one block; grid (8,32) =================
__global__ __launch_bounds__(256) void invbuild(const unsigned short* __restrict__ Lb,
    unsigned short* __restrict__ U128) {
  int ib = blockIdx.x, bh = blockIdx.y;
  int t = threadIdx.x, w = t >> 6, l = t & 63, fr = l & 15, fq = l >> 4;
  int s0 = ib * 128;
  size_t base = (size_t)bh << 20;
  unsigned short* Uo = U128 + (((size_t)(bh * 8 + ib)) << 14);
  __shared__ float LD[2][64 * 65];
  __shared__ unsigned short UaR[64 * 72];
  __shared__ unsigned short UcR[64 * 72];
  __shared__ unsigned short UaT[64 * 64];
  __shared__ unsigned short T1T[64 * 64];
#pragma unroll
  for (int i = 0; i < 32; ++i) {
    int lin = t + i * 256;
    int blk = lin >> 12, s = (lin >> 6) & 63, r = lin & 63;
    LD[blk][s * 65 + r] = -bf2f(Lb[base + ((size_t)(s0 + blk * 64 + s) << 10) + s0 + blk * 64 + r]);
  }
  __syncthreads();
  if (t < 128) {
    int blk = t >> 6, j = t & 63;
    const float* ld = LD[blk];
    float cc[64];
#pragma unroll
    for (int s = 0; s < 64; ++s) cc[s] = (s == j) ? 1.f : 0.f;
#pragma unroll
    for (int r = 0; r < 63; ++r) {
      float val = cc[r];
#pragma unroll
      for (int s = r + 1; s < 64; ++s) cc[s] -= ld[s * 65 + r] * val;
    }
    if (blk == 0) {
#pragma unroll
      for (int s = 0; s < 64; ++s) {
        unsigned short v = f2bf(cc[s]);
        UaR[s * 72 + j] = v;
        *(unsigned short*)((char*)UaT + (((j << 7) + (s << 1)) ^ ((j & 7) << 4))) = v;
      }
    } else {
#pragma unroll
      for (int s = 0; s < 64; ++s) UcR[s * 72 + j] = f2bf(cc[s]);
    }
  }
  __syncthreads();
#pragma unroll
  for (int i = 0; i < 8; ++i) {
    int cid = t + i * 256;
    int row = cid >> 4, ch = cid & 15;
    u16x8 v = {0, 0, 0, 0, 0, 0, 0, 0};
    if (row < 64) {
      if (ch < 8) {
#pragma unroll
        for (int e = 0; e < 8; ++e) v[e] = UaR[row * 72 + ch * 8 + e];
      }
      *(u16x8*)(Uo + row * 128 + ch * 8) = v;
    } else if (ch >= 8) {
#pragma unroll
      for (int e = 0; e < 8; ++e) v[e] = UcR[(row - 64) * 72 + (ch - 8) * 8 + e];
      *(u16x8*)(Uo + row * 128 + ch * 8) = v;
    }
  }
  f32x4 a1[4];
#pragma unroll
  for (int c = 0; c < 4; ++c) a1[c] = (f32x4){0.f, 0.f, 0.f, 0.f};
#pragma unroll
  for (int kc = 0; kc < 2; ++kc) {
    s16x8 af = *(const s16x8*)(Lb + base + ((size_t)(s0 + 64 + 16 * w + fr) << 10) + s0 + kc * 32 + fq * 8);
#pragma unroll
    for (int c = 0; c < 4; ++c) {
      int j = 16 * c + fr;
      s16x8 bb = *(const s16x8*)((char*)UaT + (((j << 7) + (kc << 6) + (fq << 4)) ^ ((j & 7) << 4)));
      a1[c] = __builtin_amdgcn_mfma_f32_16x16x32_bf16(af, bb, a1[c], 0, 0, 0);
    }
  }
#pragma unroll
  for (int c = 0; c < 4; ++c) {
    int gj = 16 * c + fr;
    int sb = 16 * w + fq * 4;
    u16x4 pk;
#pragma unroll
    for (int r = 0; r < 4; ++r) pk[r] = f2bf(a1[c][r]);
    *(u16x4*)((char*)T1T + (((gj << 7) + (sb << 1)) ^ ((gj & 7) << 4))) = pk;
  }
  __syncthreads();
  f32x4 a2[4];
#pragma unroll
  for (int c = 0; c < 4; ++c) a2[c] = (f32x4){0.f, 0.f, 0.f, 0.f};
#pragma unroll
  for (int kc = 0; kc < 2; ++kc) {
    s16x8 af = *(const s16x8*)(UcR + (16 * w + fr) * 72 + kc * 32 + fq * 8);
#pragma unroll
    for (int c = 0; c < 4; ++c) {
      int j = 16 * c + fr;
      s16x8 bb = *(const s16x8*)((char*)T1T + (((j << 7) + (kc << 6) + (fq << 4)) ^ ((j & 7) << 4)));
      a2[c] = __builtin_amdgcn_mfma_f32_16x16x32_bf16(af, bb, a2[c], 0, 0, 0);
    }
  }
#pragma unroll
  for (int c = 0; c < 4; ++c) {
    int gj = 16 * c + fr;
#pragma unroll
    for (int r = 0; r < 4; ++r)
      Uo[(64 + 16 * w + fq * 4 + r) * 128 + gj] = f2bf(a2[c][r]);
  }
}

// ================= u256build: B256 = Uc128 @ (Lneg_BA @ Ua128); grid (4,32) =================
__global__ __launch_bounds__(256) void u256build(const unsigned short* __restrict__ Lb,
    const unsigned short* __restrict__ U128, unsigned short* __restrict__ B256) {
  int qb = blockIdx.x, bh = blockIdx.y;
  int t = threadIdx.x, w = t >> 6, l = t & 63, fr = l & 15, fq = l >> 4;
  int s0 = qb * 256;
  size_t base = (size_t)bh << 20;
  const unsigned short* Ua = U128 + (((size_t)(bh * 8 + 2 * qb)) << 14);
  const unsigned short* Uc = U128 + (((size_t)(bh * 8 + 2 * qb + 1)) << 14);
  unsigned short* out = B256 + (((size_t)(bh * 4 + qb)) << 14);
  __shared__ unsigned short UaT[16384];
  __shared__ unsigned short T1T[16384];
#pragma unroll
  for (int i = 0; i < 8; ++i) {
    int cid = t + i * 256;
    int s = cid >> 4, ch = cid & 15;
    u16x8 v = *(const u16x8*)(Ua + s * 128 + ch * 8);
#pragma unroll
    for (int e = 0; e < 8; ++e) {
      int j = ch * 8 + e;
      int byt = ((j << 8) + (s << 1)) ^ ((j & 15) << 4);
      *(unsigned short*)((char*)UaT + byt) = v[e];
    }
  }
  __syncthreads();
  f32x4 a1[2][8];
#pragma unroll
  for (int m = 0; m < 2; ++m)
#pragma unroll
    for (int c = 0; c < 8; ++c) a1[m][c] = (f32x4){0.f, 0.f, 0.f, 0.f};
#pragma unroll
  for (int kc = 0; kc < 4; ++kc) {
    s16x8 af[2];
#pragma unroll
    for (int m = 0; m < 2; ++m)
      af[m] = *(const s16x8*)(Lb + base + ((size_t)(s0 + 128 + 32 * w + 16 * m + fr) << 10) + s0 + kc * 32 + fq * 8);
#pragma unroll
    for (int c = 0; c < 8; ++c) {
      int j = 16 * c + fr;
      s16x8 bb = *(const s16x8*)((char*)UaT + (((j << 8) + (kc << 6) + (fq << 4)) ^ ((j & 15) << 4)));
#pragma unroll
      for (int m = 0; m < 2; ++m)
        a1[m][c] = __builtin_amdgcn_mfma_f32_16x16x32_bf16(af[m], bb, a1[m][c], 0, 0, 0);
    }
  }
#pragma unroll
  for (int m = 0; m < 2; ++m) {
#pragma unroll
    for (int c = 0; c < 8; ++c) {
      int col = 16 * c + fr;
      int row0 = 32 * w + 16 * m + fq * 4;
      u16x4 pk;
#pragma unroll
      for (int r = 0; r < 4; ++r) pk[r] = f2bf(a1[m][c][r]);
      int byt = ((col << 8) + (row0 << 1)) ^ ((col & 15) << 4);
      *(u16x4*)((char*)T1T + byt) = pk;
    }
  }
  __syncthreads();
  f32x4 a2[2][8];
#pragma unroll
  for (int m = 0; m < 2; ++m)
#pragma unroll
    for (int c = 0; c < 8; ++c) a2[m][c] = (f32x4){0.f, 0.f, 0.f, 0.f};
#pragma unroll
  for (int kc = 0; kc < 4; ++kc) {
    s16x8 af[2];
#pragma unroll
    for (int m = 0; m < 2; ++m)
      af[m] = *(const s16x8*)(Uc + (32 * w + 16 * m + fr) * 128 + kc * 32 + fq * 8);
#pragma unroll
    for (int c = 0; c < 8; ++c) {
      int j = 16 * c + fr;
      s16x8 bb = *(const s16x8*)((char*)T1T + (((j << 8) + (kc << 6) + (fq << 4)) ^ ((j & 15) << 4)));
#pragma unroll
      for (int m = 0; m < 2; ++m)
        a2[m][c] = __builtin_amdgcn_mfma_f32_16x16x32_bf16(af[m], bb, a2[m][c], 0, 0, 0);
    }
  }
#pragma unroll
  for (int m = 0; m < 2; ++m) {
#pragma unroll
    for (int c = 0; c < 8; ++c) {
      int col = 16 * c + fr;
#pragma unroll
      for (int r = 0; r < 4; ++r)
        out[(32 * w + 16 * m + fq * 4 + r) * 128 + col] = f2bf(a2[m][c][r]);
    }
  }
}

// ================= solve256: 256-row band step; pipelined band GEMM + 3-piece apply =================
__global__ __launch_bounds__(256) void solve256(const unsigned short* __restrict__ WN,
    const unsigned short* __restrict__ Kk, const unsigned short* __restrict__ Lb,
    const unsigned short* __restrict__ U128, const unsigned short* __restrict__ B256,
    unsigned short* __restrict__ CT, int ib) {
  int jb = blockIdx.x, bh = blockIdx.y;
  int b = bh >> 4, h = bh & 15;
  int t = threadIdx.x, w = t >> 6, l = t & 63, fr = l & 15, fq = l >> 4;
  int s0 = ib * 256, j0 = jb * 128;
  size_t base = (size_t)bh << 20;
  __shared__ unsigned short sh[49152];      // 96KB: As[2] @0/16384, Bs[2] @32768/40960; rT aliases @0
  unsigned short* rT = sh;
  const unsigned short* Wb_ = WN + ((size_t)b << 20) + h * 64;
  const unsigned short* Kb_ = Kk + ((size_t)b << 20) + h * 64;

  f32x4 acc[4][8];
#pragma unroll
  for (int m = 0; m < 4; ++m)
#pragma unroll
    for (int c = 0; c < 8; ++c) acc[m][c] = (f32x4){0.f, 0.f, 0.f, 0.f};
  int nst = 1 + 4 * ib - 2 * jb; if (nst < 1) nst = 1;

#define STAGE_SV(buf, stp) {                                            \
  int rb = 2 * jb + (stp) - 1;                                          \
  _Pragma("unroll")                                                     \
  for (int i = 0; i < 8; ++i) {                                         \
    int cid = t + i * 256;                                              \
    int row = cid >> 3, ch = cid & 7;                                   \
    int chs = ch ^ (row & 7);                                           \
    const unsigned short* ga = ((stp) == 0)                             \
      ? Wb_ + ((size_t)(s0 + row) << 10) + chs * 8                      \
      : Lb + base + ((size_t)(s0 + row) << 10) + rb * 64 + chs * 8;     \
    glds16(ga, (char*)(sh + (buf) * 16384) + cid * 16);                 \
  }                                                                     \
  _Pragma("unroll")                                                     \
  for (int i = 0; i < 4; ++i) {                                         \
    int cid = t + i * 256;                                              \
    int row = cid >> 3, ch = cid & 7;                                   \
    int chs = ch ^ (row & 7);                                           \
    const unsigned short* gb = ((stp) == 0)                             \
      ? Kb_ + ((size_t)(j0 + row) << 10) + chs * 8                      \
      : CT + base + ((size_t)(j0 + row) << 10) + rb * 64 + chs * 8;     \
    glds16(gb, (char*)(sh + 32768 + (buf) * 8192) + cid * 16);          \
  } }

  STAGE_SV(0, 0);
  pipe_drain_barrier();
  int cur = 0;
  for (int st = 0; st < nst; ++st) {
    if (st + 1 < nst) STAGE_SV(cur ^ 1, st + 1);
    const char* Ab = (const char*)(sh + cur * 16384);
    const char* Bb = (const char*)(sh + 32768 + cur * 8192);
    __builtin_amdgcn_s_setprio(1);
#pragma unroll
    for (int kh = 0; kh < 2; ++kh) {
      s16x8 af[4], bfv[8];
#pragma unroll
      for (int m = 0; m < 4; ++m) {
        int ra = 64 * w + 16 * m + fr;
        af[m] = *(const s16x8*)(Ab + (((ra << 7) + (kh << 6) + (fq << 4)) ^ ((ra & 7) << 4)));
      }
#pragma unroll
      for (int c = 0; c < 8; ++c) {
        int rb2 = 16 * c + fr;
        bfv[c] = *(const s16x8*)(Bb + (((rb2 << 7) + (kh << 6) + (fq << 4)) ^ ((rb2 & 7) << 4)));
      }
#pragma unroll
      for (int m = 0; m < 4; ++m)
#pragma unroll
        for (int c = 0; c < 8; ++c)
          acc[m][c] = __builtin_amdgcn_mfma_f32_16x16x32_bf16(af[m], bfv[c], acc[m][c], 0, 0, 0);
    }
    __builtin_amdgcn_s_setprio(0);
    pipe_drain_barrier();
    cur ^= 1;
  }
#undef STAGE_SV
  // write rectT [j][s] (512B rows, XOR (j&15)<<4), mask j >= s
#pragma unroll
  for (int m = 0; m < 4; ++m) {
#pragma unroll
    for (int c = 0; c < 8; ++c) {
      int sl0 = 64 * w + 16 * m + fq * 4;
      int jl = 16 * c + fr;
      u16x4 pk;
#pragma unroll
      for (int r = 0; r < 4; ++r) {
        float v = acc[m][c][r];
        if (j0 + jl >= s0 + sl0 + r) v = 0.f;
        pk[r] = f2bf(v);
      }
      int byt = ((jl << 9) + (sl0 << 1)) ^ ((jl & 15) << 4);
      *(u16x4*)((char*)rT + byt) = pk;
    }
  }
  __syncthreads();
  const unsigned short* Ua = U128 + (((size_t)(bh * 8 + 2 * ib)) << 14);
  const unsigned short* Uc = U128 + (((size_t)(bh * 8 + 2 * ib + 1)) << 14);
  const unsigned short* Bm = B256 + (((size_t)(bh * 4 + ib)) << 14);
#pragma unroll
  for (int m = 0; m < 4; ++m)
#pragma unroll
    for (int c = 0; c < 8; ++c) acc[m][c] = (f32x4){0.f, 0.f, 0.f, 0.f};
  int nkc = (w < 2) ? 4 : 8;
  for (int kc = 0; kc < nkc; ++kc) {
    const unsigned short* src; int arow;
    if (w < 2) { src = Ua; arow = 64 * w; }
    else { src = (kc < 4) ? Bm : Uc; arow = 64 * (w - 2); }
    s16x8 uf[4];
#pragma unroll
    for (int m = 0; m < 4; ++m)
      uf[m] = *(const s16x8*)(src + (arow + 16 * m + fr) * 128 + (kc & 3) * 32 + fq * 8);
#pragma unroll
    for (int c = 0; c < 8; ++c) {
      int jl = 16 * c + fr;
      s16x8 bb = *(const s16x8*)((char*)rT + (((jl << 9) + (kc << 6) + (fq << 4)) ^ ((jl & 15) << 4)));
#pragma unroll
      for (int m = 0; m < 4; ++m)
        acc[m][c] = __builtin_amdgcn_mfma_f32_16x16x32_bf16(uf[m], bb, acc[m][c], 0, 0, 0);
    }
  }
#pragma unroll
  for (int m = 0; m < 4; ++m) {
#pragma unroll
    for (int c = 0; c < 8; ++c) {
      int jl = 16 * c + fr;
      int sb = 64 * w + 16 * m + fq * 4;
      u16x4 pk;
#pragma unroll
      for (int r = 0; r < 4; ++r) pk[r] = f2bf(acc[m][c][r]);
      *(u16x4*)(CT + base + ((size_t)(j0 + jl) << 10) + s0 + sb) = pk;
    }
  }
}

// ================= pv: online-softmax + P @ V; wave-independent (no barriers) =================
__global__ __launch_bounds__(256) void pv_kernel(const unsigned short* __restrict__ S,
    const unsigned short* __restrict__ VT, const float* __restrict__ Fc,
    unsigned short* __restrict__ Ob) {
  int idx = blockIdx.x;
  int bh = idx & 31, rank = idx >> 5;
  int tb = 15 - rank;
  int b = bh >> 4, h = bh & 15;
  int t0 = tb * 64;
  int t = threadIdx.x, w = t >> 6, l = t & 63, fr = l & 15, fq = l >> 4;
  int g = l >> 3, ch = l & 7;              // 8-lane row group / col chunk
  __shared__ unsigned short Pl[4][16 * 64];   // per-wave 2KB region
  size_t base = (size_t)bh << 20;
  float m0 = -1e30f, m1 = -1e30f, l0 = 0.f, l1 = 0.f;
  f32x4 acc[4];
#pragma unroll
  for (int c = 0; c < 4; ++c) acc[c] = (f32x4){0.f,0.f,0.f,0.f};
  for (int jb = 0; jb <= tb; ++jb) {
    int j0 = jb * 64;
    float sc[2];
#pragma unroll
    for (int i = 0; i < 2; ++i) {
      int row16 = g + i * 8;
      int row64 = 16 * w + row16;
      int grow = t0 + row64;
      u16x8 sv = *(const u16x8*)(S + base + ((size_t)grow << 10) + j0 + ch * 8);
      float4 f0 = *(const float4*)(Fc + bh * 1024 + j0 + ch * 8);
      float4 f1 = *(const float4*)(Fc + bh * 1024 + j0 + ch * 8 + 4);
      float vals[8];
      float tm = -1e30f;
#pragma unroll
      for (int e = 0; e < 8; ++e) {
        float fc = e < 4 ? ((const float*)&f0)[e] : ((const float*)&f1)[e - 4];
        float v = bf2f(sv[e]) * SM_SCALE - fc;
        if (jb == tb && ch * 8 + e > row64) v = -1e30f;
        vals[e] = v; tm = fmaxf(tm, v);
      }
      tm = fmaxf(tm, __shfl_xor(tm, 1));
      tm = fmaxf(tm, __shfl_xor(tm, 2));
      tm = fmaxf(tm, __shfl_xor(tm, 4));
      float mo = i ? m1 : m0;
      float mn = fmaxf(mo, tm);
      float s = __expf(mo - mn);
      u16x8 pv;
      float psum = 0.f;
#pragma unroll
      for (int e = 0; e < 8; ++e) {
        float p = __expf(vals[e] - mn);
        psum += p; pv[e] = f2bf(p);
      }
      int byt = ((row16 << 7) + (ch << 4)) ^ ((row16 & 7) << 4);
      *(u16x8*)((char*)Pl[w] + byt) = pv;
      psum += __shfl_xor(psum, 1);
      psum += __shfl_xor(psum, 2);
      psum += __shfl_xor(psum, 4);
      if (i) { m1 = mn; l1 = l1 * s + psum; } else { m0 = mn; l0 = l0 * s + psum; }
      sc[i] = s;
    }
    __builtin_amdgcn_wave_barrier();
    float cr[4];
#pragma unroll
    for (int r = 0; r < 4; ++r) {
      int rho = fq * 4 + r;
      int src = (rho & 7) * 8;
      float v0 = __shfl(sc[0], src);
      float v1 = __shfl(sc[1], src);
      cr[r] = (rho < 8) ? v0 : v1;
    }
#pragma unroll
    for (int c = 0; c < 4; ++c)
#pragma unroll
      for (int r = 0; r < 4; ++r) acc[c][r] *= cr[r];
#pragma unroll
    for (int kh = 0; kh < 2; ++kh) {
      s16x8 a = *(const s16x8*)((char*)Pl[w] + (((fr << 7) + (kh << 6) + (fq << 4)) ^ ((fr & 7) << 4)));
#pragma unroll
      for (int c = 0; c < 4; ++c) {
        s16x8 bb = *(const s16x8*)(VT + ((size_t)bh * 64 + 16 * c + fr) * 1024 + j0 + kh * 32 + fq * 8);
        acc[c] = __builtin_amdgcn_mfma_f32_16x16x32_bf16(a, bb, acc[c], 0, 0, 0);
      }
    }
    __builtin_amdgcn_wave_barrier();
  }
  float inv[4];
#pragma unroll
  for (int r = 0; r < 4; ++r) {
    int rho = fq * 4 + r;
    int src = (rho & 7) * 8;
    float v0 = __shfl(l0, src);
    float v1 = __shfl(l1, src);
    inv[r] = 1.f / ((rho < 8) ? v0 : v1);
  }
#pragma unroll
  for (int c = 0; c < 4; ++c) {
#pragma unroll
    for (int r = 0; r < 4; ++r) {
      int grow = t0 + 16 * w + fq * 4 + r;
      Ob[((size_t)(b * 1024) + grow) * 1024 + h * 64 + 16 * c + fr] = f2bf(acc[c][r] * inv[r]);
    }
  }
}

extern "C" void kernel_launch(void* const* d_in, const int* in_sizes, int n_in,
                              void* d_out, int out_size, void* d_ws, size_t ws_size,
                              hipStream_t stream) {
  const float* x    = (const float*)d_in[0];
  const float* Wq   = (const float*)d_in[1];
  const float* Wk   = (const float*)d_in[2];
  const float* Wv   = (const float*)d_in[3];
  const float* Wo   = (const float*)d_in[4];
  const float* Ww1  = (const float*)d_in[5];
  const float* Ww2  = (const float*)d_in[6];
  const float* Wb   = (const float*)d_in[7];
  const float* Wf   = (const float*)d_in[8];
  const float* delta= (const float*)d_in[9];

  char* ws = (char*)d_ws;
  unsigned short* xb   = (unsigned short*)(ws + OFF_XB);
  unsigned short* WqT  = (unsigned short*)(ws + OFF_WQT);
  unsigned short* WkT  = (unsigned short*)(ws + OFF_WKT);
  unsigned short* WvT  = (unsigned short*)(ws + OFF_WVT);
  unsigned short* WoT  = (unsigned short*)(ws + OFF_WOT);
  unsigned short* W1c  = (unsigned short*)(ws + OFF_W1C);
  unsigned short* W2T  = (unsigned short*)(ws + OFF_W2T);
  float*          Beta = (float*)(ws + OFF_BETA);
  unsigned short* Q16  = (unsigned short*)(ws + OFF_Q16);
  unsigned short* K16  = (unsigned short*)(ws + OFF_K16);
  unsigned short* VT   = (unsigned short*)(ws + OFF_VT);
  unsigned short* WN16 = (unsigned short*)(ws + OFF_WN16);
  unsigned short* WB16 = (unsigned short*)(ws + OFF_WB16);
  unsigned short* WNF16= (unsigned short*)(ws + OFF_WNF);
  unsigned short* ObB  = (unsigned short*)(ws + OFF_OB);
  unsigned short* BFT  = (unsigned short*)(ws + OFF_BFT);
  float*          Fc   = (float*)(ws + OFF_FC);
  unsigned short* Lbuf = (unsigned short*)(ws + OFF_L);
  unsigned short* Sbuf = (unsigned short*)(ws + OFF_L);
  unsigned short* CT   = (unsigned short*)(ws + OFF_CT);
  unsigned short* Gbuf = (unsigned short*)(ws + OFF_G);
  float*          BL   = (float*)(ws + OFF_BL);
  unsigned short* U128 = (unsigned short*)(ws + OFF_U128);
  unsigned short* B256 = (unsigned short*)(ws + OFF_B256);

  dim3 blk(256);
  // prep (all transposes + casts + BFT 128-row; vectorized transposes)
  prep_all<<<2160, blk, 0, stream>>>(Wq, Wk, Wv, Wo, Ww1, Ww2, x, Wb, Wf,
                                     WqT, WkT, WvT, WoT, W1c, W2T, xb, BFT);
  // WfusedT (256 tiles) + BL (32 tiles) in one 288-block launch
  wfuse_bl<<<288, blk, 0, stream>>>(W2T, W1c, xb, BFT, WN16, BL);
  // Q, K, VT, WNF in one 512-block launch (XCD-grouped, pipelined, no tail)
  proj_big<<<512, blk, 0, stream>>>(xb, WqT, WkT, WvT, WN16, Q16, K16, VT, WNF16);
  // beta/logsigmoid/cumsum fused
  bgfc<<<32, blk, 0, stream>>>(BL, delta, Beta, Fc);
  wnorm2<<<2048, blk, 0, stream>>>(WNF16, Beta, WN16, WB16);
  // L and G (both stored NEGATED)
  pairLG<<<dim3(36 * 32), blk, 0, stream>>>(WN16, Q16, WB16, Lbuf, Gbuf);
  // triangular solve: fused inverses -> 256 off-diag piece -> 4 band steps
  invbuild<<<dim3(8,32), blk, 0, stream>>>(Lbuf, U128);
  u256build<<<dim3(4,32), blk, 0, stream>>>(Lbuf, U128, B256);
  for (int ib = 0; ib < 4; ++ib)
    solve256<<<dim3(2 * ib + 2, 32), blk, 0, stream>>>(WN16, K16, Lbuf, U128, B256, CT, ib);
  // S = QK^T + Gneg C (sorted band grid; reuses L region; pipelined)
  score128s<<<dim3(36 * 32), blk, 0, stream>>>(Q16, K16, Gbuf, CT, Sbuf);
  // online softmax + PV (wave-independent)
  pv_kernel<<<dim3(512), blk, 0, stream>>>(Sbuf, VT, Fc, ObB);
  // output projection (f32 out; 128x64 tiles, single round, XCD-grouped)
  gemm_outproj<<<256, blk, 0, stream>>>(ObB, WoT, (float*)d_out);
}